// Round 10
// baseline (254.378 us; speedup 1.0000x reference)
//
#include <hip/hip_runtime.h>
#include <cstdint>
#include <cstddef>

typedef __attribute__((ext_vector_type(8))) short bf16x8;
typedef __attribute__((ext_vector_type(4))) float f32x4;

__device__ __forceinline__ unsigned short f2bf(float f) {
  union { float f; unsigned int u; } v; v.f = f;
  unsigned int r = v.u + 0x7fffu + ((v.u >> 16) & 1u);
  return (unsigned short)(r >> 16);
}

// ============================================================================
// Btile layout (BK=32 steps): per (n-panel p of 128 rows, k-step s of 32):
// 512 slots of 16B; slot = r*4 + c4 holds B[n0+r][s*32 + (c4 ^ ((r>>1)&3))*8 .. +8].
// Panel stride = K*128 shorts; step stride = 4096 shorts.
// GEMM reads fragments DIRECTLY from global (no LDS): lane (fl,q) of wave at wn:
//   gb = Bt + (wn+fl)*32 + (q ^ ((fl>>1)&3))*8 ; frag j at +j*512 ; +4096/iter.
// A fragments direct from row-major bf16: a_u = rowptr(m0+wm+u*16+fl) + q*8 ; +32/iter.
// ============================================================================

// ---------------- weight transposes (tiled, gate/up fused) + x cast + router logits ----------------
// z 0..7: Wg[e]+Wu[e] -> WguT[e] (both parities); z 8..15: Wd[e] -> WdT[e] (K=512)
// z 16: Sg+Su -> SguT; z 17: Sd -> SdT; z 18..21: x -> Xb cast; z 22: logits
__global__ __launch_bounds__(256) void transpose_cvt_all(
    const float* __restrict__ Wg, const float* __restrict__ Wu,
    const float* __restrict__ Wd, const float* __restrict__ Sg,
    const float* __restrict__ Su, const float* __restrict__ Sd,
    const float* __restrict__ x, const float* __restrict__ Wr,
    unsigned short* __restrict__ WguT, unsigned short* __restrict__ WdT,
    unsigned short* __restrict__ SguT, unsigned short* __restrict__ SdT,
    unsigned short* __restrict__ Xb, float* __restrict__ logits) {
  const int z = blockIdx.z;
  const int tid = threadIdx.x;

  if (z == 22) {  // ---- router logits: 8 tokens per block ----
    const int bid = blockIdx.y * 16 + blockIdx.x;   // 0..255
    const int wave = tid >> 6;
    const int lane = tid & 63;
#pragma unroll
    for (int it = 0; it < 2; it++) {
      const int t = bid * 8 + wave * 2 + it;
      const float* xr = x + (size_t)t * 1024;
      float acc[8];
#pragma unroll
      for (int e = 0; e < 8; e++) acc[e] = 0.f;
#pragma unroll
      for (int i = 0; i < 16; i++) {
        int d = lane + i * 64;
        float xv = xr[d];
        const float4* w = (const float4*)(Wr + d * 8);
        float4 w0 = w[0], w1 = w[1];
        acc[0] += xv * w0.x; acc[1] += xv * w0.y; acc[2] += xv * w0.z; acc[3] += xv * w0.w;
        acc[4] += xv * w1.x; acc[5] += xv * w1.y; acc[6] += xv * w1.z; acc[7] += xv * w1.w;
      }
#pragma unroll
      for (int off = 32; off > 0; off >>= 1)
#pragma unroll
        for (int e = 0; e < 8; e++) acc[e] += __shfl_down(acc[e], off);
      if (lane == 0) {
#pragma unroll
        for (int e = 0; e < 8; e++) logits[t * 8 + e] = acc[e];
      }
    }
    return;
  }

  if (z >= 18) {  // ---- copy-cast x (row-major bf16) ----
    size_t off = (size_t)(z - 18) * 524288 + blockIdx.y * 32768 + blockIdx.x * 2048 + tid * 8;
    const float4* s = (const float4*)(x + off);
    float4 a = s[0], b = s[1];
    bf16x8 o = { (short)f2bf(a.x), (short)f2bf(a.y), (short)f2bf(a.z), (short)f2bf(a.w),
                 (short)f2bf(b.x), (short)f2bf(b.y), (short)f2bf(b.z), (short)f2bf(b.w) };
    *(bf16x8*)(Xb + off) = o;
    return;
  }

  __shared__ float tg[64][65];
  __shared__ float tu[64][65];

  if (z < 8 || z == 16) {  // ---- fused gate/up planes ----
    const float* sg_; const float* su_; unsigned short* base; int C;
    if (z < 8) { sg_ = Wg + (size_t)z * 524288; su_ = Wu + (size_t)z * 524288;
                 base = WguT + (size_t)z * 1048576; C = 512; }
    else       { sg_ = Sg; su_ = Su; base = SguT; C = 1024; }
    const int c0 = blockIdx.x * 64, r0 = blockIdx.y * 64;
    if (c0 >= C) return;
    {
      const int row = tid >> 2, cs = (tid & 3) * 16;
      const float* spg = sg_ + (size_t)(r0 + row) * C + c0 + cs;
      const float* spu = su_ + (size_t)(r0 + row) * C + c0 + cs;
#pragma unroll
      for (int k = 0; k < 4; k++) {
        float4 v = ((const float4*)spg)[k];
        tg[row][cs + k * 4 + 0] = v.x; tg[row][cs + k * 4 + 1] = v.y;
        tg[row][cs + k * 4 + 2] = v.z; tg[row][cs + k * 4 + 3] = v.w;
      }
#pragma unroll
      for (int k = 0; k < 4; k++) {
        float4 v = ((const float4*)spu)[k];
        tu[row][cs + k * 4 + 0] = v.x; tu[row][cs + k * 4 + 1] = v.y;
        tu[row][cs + k * 4 + 2] = v.z; tu[row][cs + k * 4 + 3] = v.w;
      }
    }
    __syncthreads();
#pragma unroll
    for (int i = 0; i < 2; i++) {
      const int cc = i * 32 + (tid >> 3);
      const int rseg = (tid & 7) * 8;
      bf16x8 og, ou;
#pragma unroll
      for (int j = 0; j < 8; j++) {
        og[j] = (short)f2bf(tg[rseg + j][cc]);
        ou[j] = (short)f2bf(tu[rseg + j][cc]);
      }
      const int f = c0 + cc;              // gate row 2f, up row 2f+1
      const int k0 = r0 + rseg;
      const int p = f >> 6;               // = (2f)>>7
      const int rg = (2 * f) & 127;
      const int s = k0 >> 5;
      const int c4 = ((k0 >> 3) & 3) ^ (f & 3);   // key (rg>>1)&3 == (ru>>1)&3 == f&3
      unsigned short* d = base + (size_t)p * 131072 + (size_t)s * 4096 + (rg * 4 + c4) * 8;
      *(bf16x8*)d = og;
      *(bf16x8*)(d + 32) = ou;            // slot +4 = 64B -> dense 128B lines
    }
    return;
  }

  // ---- unfused planes: Wd (z 8..15, R=512) / Sd (z 17) ----
  const float* src; unsigned short* base; int R, Ksz;
  if (z < 16) { src = Wd + (size_t)(z - 8) * 524288; base = WdT + (size_t)(z - 8) * 524288; R = 512; Ksz = 512; }
  else        { src = Sd; base = SdT; R = 1024; Ksz = 1024; }
  const int C = 1024;
  const int c0 = blockIdx.x * 64, r0 = blockIdx.y * 64;
  if (r0 >= R) return;
  {
    const int row = tid >> 2, cs = (tid & 3) * 16;
    const float* sp = src + (size_t)(r0 + row) * C + c0 + cs;
#pragma unroll
    for (int k = 0; k < 4; k++) {
      float4 v = ((const float4*)sp)[k];
      tg[row][cs + k * 4 + 0] = v.x; tg[row][cs + k * 4 + 1] = v.y;
      tg[row][cs + k * 4 + 2] = v.z; tg[row][cs + k * 4 + 3] = v.w;
    }
  }
  __syncthreads();
#pragma unroll
  for (int i = 0; i < 2; i++) {
    const int cc = i * 32 + (tid >> 3);
    const int rseg = (tid & 7) * 8;
    bf16x8 o;
#pragma unroll
    for (int j = 0; j < 8; j++) o[j] = (short)f2bf(tg[rseg + j][cc]);
    const int n = c0 + cc;
    const int k0 = r0 + rseg;
    const int p = n >> 7, r = n & 127, s = k0 >> 5;
    const int c4 = ((k0 >> 3) & 3) ^ ((r >> 1) & 3);
    *(bf16x8*)(base + (size_t)p * (Ksz * 128) + (size_t)s * 4096 + (r * 4 + c4) * 8) = o;
  }
}

// ---------------- router: assignment ----------------
__global__ __launch_bounds__(1024) void assign_kernel(
    const float* __restrict__ logits, const float* __restrict__ bias,
    int* __restrict__ list, int* __restrict__ ridx, float* __restrict__ rp,
    int* __restrict__ counts_g, int* __restrict__ offs_g) {
  __shared__ int cnt[8];
  __shared__ int offs[9];
  const int tid = threadIdx.x;
  if (tid < 8) cnt[tid] = 0;
  __syncthreads();
  int te[2][2], tpos[2][2];
  float tp[2][2];
#pragma unroll
  for (int it = 0; it < 2; it++) {
    int t = tid + it * 1024;
    float v[8];
#pragma unroll
    for (int e = 0; e < 8; e++) v[e] = logits[t * 8 + e] + bias[e];
    int i0 = 0;
#pragma unroll
    for (int e = 1; e < 8; e++) if (v[e] > v[i0]) i0 = e;
    int i1 = (i0 == 0) ? 1 : 0;
#pragma unroll
    for (int e = 0; e < 8; e++) if (e != i0 && v[e] > v[i1]) i1 = e;
    float pa = 1.f / (1.f + __expf(v[i1] - v[i0]));
    te[it][0] = i0; te[it][1] = i1;
    tp[it][0] = pa; tp[it][1] = 1.f - pa;
    tpos[it][0] = atomicAdd(&cnt[i0], 1);
    tpos[it][1] = atomicAdd(&cnt[i1], 1);
  }
  __syncthreads();
  if (tid == 0) {
    int s = 0;
#pragma unroll
    for (int e = 0; e < 8; e++) { offs[e] = s; s += cnt[e]; }
    offs[8] = s;
#pragma unroll
    for (int e = 0; e < 8; e++) { counts_g[e] = cnt[e]; offs_g[e] = offs[e]; }
    offs_g[8] = s;
  }
  __syncthreads();
#pragma unroll
  for (int it = 0; it < 2; it++) {
    int t = tid + it * 1024;
#pragma unroll
    for (int k = 0; k < 2; k++) {
      int grow = offs[te[it][k]] + tpos[it][k];
      list[grow] = t;
      ridx[t * 2 + k] = grow;
      rp[t * 2 + k] = tp[it][k];
    }
  }
}

// ---------------- register-direct K-loop: no LDS, no barriers ----------------
// Per lane: 8 x global_load_dwordx4 per iter (4 A frags from row ptrs, 4 B frags from Btile),
// register double-buffered one K-step ahead; compiler inserts vmcnt waits.
template <int NK>
__device__ __forceinline__ void kloop_reg(
    const unsigned short* a0, const unsigned short* a1,
    const unsigned short* a2, const unsigned short* a3,
    const unsigned short* gb,
    f32x4 (&acc)[4][4]) {
  bf16x8 af[2][4], bf[2][4];
  af[0][0] = *(const bf16x8*)(a0);
  af[0][1] = *(const bf16x8*)(a1);
  af[0][2] = *(const bf16x8*)(a2);
  af[0][3] = *(const bf16x8*)(a3);
  bf[0][0] = *(const bf16x8*)(gb);
  bf[0][1] = *(const bf16x8*)(gb + 512);
  bf[0][2] = *(const bf16x8*)(gb + 1024);
  bf[0][3] = *(const bf16x8*)(gb + 1536);
#pragma unroll
  for (int i = 0; i < NK; ++i) {
    const int cur = i & 1, nxt = cur ^ 1;   // static after full unroll (rule #20 safe)
    if (i + 1 < NK) {
      const int ao = (i + 1) * 32;
      const int bo = (i + 1) * 4096;
      af[nxt][0] = *(const bf16x8*)(a0 + ao);
      af[nxt][1] = *(const bf16x8*)(a1 + ao);
      af[nxt][2] = *(const bf16x8*)(a2 + ao);
      af[nxt][3] = *(const bf16x8*)(a3 + ao);
      bf[nxt][0] = *(const bf16x8*)(gb + bo);
      bf[nxt][1] = *(const bf16x8*)(gb + bo + 512);
      bf[nxt][2] = *(const bf16x8*)(gb + bo + 1024);
      bf[nxt][3] = *(const bf16x8*)(gb + bo + 1536);
    }
    __builtin_amdgcn_s_setprio(1);
#pragma unroll
    for (int ii = 0; ii < 4; ++ii)
#pragma unroll
      for (int jj = 0; jj < 4; ++jj)
        acc[ii][jj] = __builtin_amdgcn_mfma_f32_16x16x32_bf16(af[cur][ii], bf[cur][jj], acc[ii][jj], 0, 0, 0);
    __builtin_amdgcn_s_setprio(0);
  }
}

// ---------------- fused TN GEMM: 128x128 tile, 4 waves, LDS-free, XCD-class remap ----------------
template <int MODE>
__global__ __launch_bounds__(256, 3) void gemm_tn_kernel(
    const unsigned short* __restrict__ Xb, const unsigned short* __restrict__ He,
    const unsigned short* __restrict__ Hs, const unsigned short* __restrict__ Wgu,
    const unsigned short* __restrict__ Sgu, const unsigned short* __restrict__ Wd,
    const unsigned short* __restrict__ Sd, unsigned short* __restrict__ HeOut,
    unsigned short* __restrict__ HsOut, float* __restrict__ De, float* __restrict__ Ds,
    const int* __restrict__ list, const int* __restrict__ counts,
    const int* __restrict__ offs) {
  const int h = blockIdx.x;
  const int c = h & 7;
  const int idx = h >> 3;

  int cnt, lda, m0, n0;
  bool routed;
  const unsigned short* A;
  const unsigned short* Bt;
  const int* alist = nullptr;
  unsigned short* H = nullptr;
  float* D = nullptr;
  int ldh = 0;

  if (MODE == 0) {
    if (idx < 128) {
      routed = true;
      n0 = (idx >> 4) * 128; m0 = (idx & 15) * 128;
      cnt = counts[c]; A = Xb; alist = list + offs[c]; lda = 1024;
      Bt = Wgu + (size_t)c * 1048576 + (size_t)(n0 >> 7) * 131072;
      H = HeOut + (size_t)offs[c] * 512; ldh = 512;
    } else {
      routed = false;
      const int t2 = idx - 128;                       // 0..31
      m0 = ((c & 1) * 8 + (t2 & 7)) * 128;
      n0 = ((c >> 1) * 4 + (t2 >> 3)) * 128;
      cnt = 2048; A = Xb; lda = 1024;
      Bt = Sgu + (size_t)(n0 >> 7) * 131072;
      H = HsOut; ldh = 1024;
    }
  } else {
    if (idx < 128) {
      routed = true;
      n0 = (idx >> 4) * 128; m0 = (idx & 15) * 128;
      cnt = counts[c]; A = He + (size_t)offs[c] * 512; lda = 512;
      Bt = Wd + (size_t)c * 524288 + (size_t)(n0 >> 7) * 65536;
      D = De + (size_t)offs[c] * 1024;
    } else {
      routed = false;
      const int t2 = idx - 128;                       // 0..15
      m0 = ((c & 1) * 8 + (t2 & 7)) * 128;
      n0 = ((c >> 1) * 2 + (t2 >> 3)) * 128;
      cnt = 2048; A = Hs; lda = 1024;
      Bt = Sd + (size_t)(n0 >> 7) * 131072;
      D = Ds;
    }
  }
  if (m0 >= cnt) return;

  const int tid = threadIdx.x;
  const int wave = tid >> 6;
  const int lane = tid & 63;
  const int wm = (wave & 1) * 64;
  const int wn = (wave >> 1) * 64;
  const int fl = lane & 15;
  const int q = lane >> 4;

  // per-lane A row pointers (frag u = rows m0+wm+u*16+fl), chunk q*8, +32/iter
  int r0 = m0 + wm + fl;      if (r0 >= cnt) r0 = cnt - 1;
  int r1 = r0 + 16;           if (r1 >= cnt) r1 = cnt - 1;
  int r2 = r0 + 32;           if (r2 >= cnt) r2 = cnt - 1;
  int r3 = r0 + 48;           if (r3 >= cnt) r3 = cnt - 1;
  size_t ab0, ab1, ab2, ab3;
  if (MODE == 0 && routed) {
    ab0 = (size_t)alist[r0] * lda; ab1 = (size_t)alist[r1] * lda;
    ab2 = (size_t)alist[r2] * lda; ab3 = (size_t)alist[r3] * lda;
  } else {
    ab0 = (size_t)r0 * lda; ab1 = (size_t)r1 * lda;
    ab2 = (size_t)r2 * lda; ab3 = (size_t)r3 * lda;
  }
  const unsigned short* a0 = A + ab0 + q * 8;
  const unsigned short* a1 = A + ab1 + q * 8;
  const unsigned short* a2 = A + ab2 + q * 8;
  const unsigned short* a3 = A + ab3 + q * 8;

  // per-lane B fragment pointer: row wn+fl, swizzled chunk (key invariant across +16 rows)
  const unsigned short* gb = Bt + (wn + fl) * 32 + (q ^ ((fl >> 1) & 3)) * 8;

  f32x4 acc[4][4];
  f32x4 zero = {0.f, 0.f, 0.f, 0.f};
#pragma unroll
  for (int i = 0; i < 4; i++)
#pragma unroll
    for (int j = 0; j < 4; j++) acc[i][j] = zero;

  if (MODE == 1 && routed) kloop_reg<16>(a0, a1, a2, a3, gb, acc);
  else                     kloop_reg<32>(a0, a1, a2, a3, gb, acc);

  if (MODE == 0) {
#pragma unroll
    for (int i = 0; i < 4; i++) {
#pragma unroll
      for (int j = 0; j < 4; j++) {
#pragma unroll
        for (int r = 0; r < 4; r++) {
          int grow = m0 + wm + i * 16 + q * 4 + r;
          float v = acc[i][j][r];
          float pv = __shfl_xor(v, 1);
          if ((lane & 1) == 0 && grow < cnt) {
            float s = v / (1.f + __expf(-v));
            int colh = (n0 + wn + j * 16 + fl) >> 1;
            H[(size_t)grow * ldh + colh] = f2bf(s * pv);
          }
        }
      }
    }
  } else {
#pragma unroll
    for (int i = 0; i < 4; i++) {
#pragma unroll
      for (int r = 0; r < 4; r++) {
        int grow = m0 + wm + i * 16 + q * 4 + r;
        if (grow >= cnt) continue;
#pragma unroll
        for (int j = 0; j < 4; j++) {
          int col = n0 + wn + j * 16 + fl;
          D[(size_t)grow * 1024 + col] = acc[i][j][r];
        }
      }
    }
  }
}

// ---------------- combine ----------------
__global__ __launch_bounds__(256) void combine_kernel(
    const float* __restrict__ Ds, const float* __restrict__ De,
    const int* __restrict__ ridx, const float* __restrict__ rp,
    float* __restrict__ out) {
  const int t = blockIdx.x;
  const int i0 = ridx[t * 2], i1 = ridx[t * 2 + 1];
  const float p0 = rp[t * 2], p1 = rp[t * 2 + 1];
  const float4* a  = (const float4*)(Ds + (size_t)t * 1024);
  const float4* b0 = (const float4*)(De + (size_t)i0 * 1024);
  const float4* b1 = (const float4*)(De + (size_t)i1 * 1024);
  float4* o = (float4*)(out + (size_t)t * 1024);
  int c = threadIdx.x;
  float4 va = a[c], v0 = b0[c], v1 = b1[c];
  float4 r;
  r.x = va.x + p0 * v0.x + p1 * v1.x;
  r.y = va.y + p0 * v0.y + p1 * v1.y;
  r.z = va.z + p0 * v0.z + p1 * v1.z;
  r.w = va.w + p0 * v0.w + p1 * v1.w;
  o[c] = r;
}

// ---------------- launch ----------------
extern "C" void kernel_launch(void* const* d_in, const int* in_sizes, int n_in,
                              void* d_out, int out_size, void* d_ws, size_t ws_size,
                              hipStream_t stream) {
  const float* x    = (const float*)d_in[0];
  const float* Wr   = (const float*)d_in[1];
  const float* Wg   = (const float*)d_in[2];
  const float* Wu   = (const float*)d_in[3];
  const float* Wd   = (const float*)d_in[4];
  const float* Sg   = (const float*)d_in[5];
  const float* Su   = (const float*)d_in[6];
  const float* Sd   = (const float*)d_in[7];
  const float* bias = (const float*)d_in[8];
  float* out = (float*)d_out;

  char* ws = (char*)d_ws;
  size_t o = 0;
  auto alloc = [&](size_t b) { char* p = ws + o; o += (b + 255) & ~(size_t)255; return p; };
  unsigned short* Xb   = (unsigned short*)alloc((size_t)2048 * 1024 * 2);
  unsigned short* WguT = (unsigned short*)alloc((size_t)8 * 1024 * 1024 * 2);
  unsigned short* WdT  = (unsigned short*)alloc((size_t)8 * 1024 * 512 * 2);
  unsigned short* SguT = (unsigned short*)alloc((size_t)2048 * 1024 * 2);
  unsigned short* SdT  = (unsigned short*)alloc((size_t)1024 * 1024 * 2);
  float* logits = (float*)alloc((size_t)2048 * 8 * 4);
  int*   list   = (int*)alloc((size_t)4096 * 4);
  int*   ridx   = (int*)alloc((size_t)2048 * 2 * 4);
  float* rp     = (float*)alloc((size_t)2048 * 2 * 4);
  int*   counts = (int*)alloc(64);
  int*   offs   = (int*)alloc(64);
  unsigned short* He = (unsigned short*)alloc((size_t)4096 * 512 * 2);
  unsigned short* Hs = (unsigned short*)alloc((size_t)2048 * 1024 * 2);
  float* De = (float*)alloc((size_t)4096 * 1024 * 4);
  float* Ds = (float*)alloc((size_t)2048 * 1024 * 4);

  transpose_cvt_all<<<dim3(16, 16, 23), 256, 0, stream>>>(Wg, Wu, Wd, Sg, Su, Sd, x, Wr,
                                                          WguT, WdT, SguT, SdT, Xb, logits);

  assign_kernel<<<1, 1024, 0, stream>>>(logits, bias, list, ridx, rp, counts, offs);

  gemm_tn_kernel<0><<<dim3(1280), 256, 0, stream>>>(
      Xb, He, Hs, WguT, SguT, WdT, SdT, He, Hs, De, Ds, list, counts, offs);
  gemm_tn_kernel<1><<<dim3(1152), 256, 0, stream>>>(
      Xb, He, Hs, WguT, SguT, WdT, SdT, He, Hs, De, Ds, list, counts, offs);

  combine_kernel<<<2048, 256, 0, stream>>>(Ds, De, ridx, rp, out);
}

// Round 11
// 210.013 us; speedup vs baseline: 1.2112x; 1.2112x over previous
//
#include <hip/hip_runtime.h>
#include <cstdint>
#include <cstddef>

typedef __attribute__((ext_vector_type(8))) short bf16x8;
typedef __attribute__((ext_vector_type(4))) float f32x4;

#define AS1 __attribute__((address_space(1)))
#define AS3 __attribute__((address_space(3)))

__device__ __forceinline__ unsigned short f2bf(float f) {
  union { float f; unsigned int u; } v; v.f = f;
  unsigned int r = v.u + 0x7fffu + ((v.u >> 16) & 1u);
  return (unsigned short)(r >> 16);
}

__device__ __forceinline__ void gll16(const unsigned short* g, unsigned short* l) {
  __builtin_amdgcn_global_load_lds((const AS1 void*)g, (AS3 void*)l, 16, 0, 0);
}

// ============================================================================
// Btile layout (BK=32 steps): per (n-panel p of 128 rows, k-step s of 32):
// 512 slots of 16B; slot = r*4 + c4 holds B[n0+r][s*32 + (c4 ^ ((r>>1)&3))*8 .. +8].
// Panel stride = K*128 shorts; step stride = 4096 shorts.
// GEMM: block tile 256x128 (M x N), 4 waves of 128x64, BK=32, 3-buf depth-2 LDS.
// ============================================================================

// ---------------- weight transposes (tiled, gate/up fused) + x cast + router logits ----------------
// z 0..7: Wg[e]+Wu[e] -> WguT[e] (both parities); z 8..15: Wd[e] -> WdT[e] (K=512)
// z 16: Sg+Su -> SguT; z 17: Sd -> SdT; z 18..21: x -> Xb cast; z 22: logits
__global__ __launch_bounds__(256) void transpose_cvt_all(
    const float* __restrict__ Wg, const float* __restrict__ Wu,
    const float* __restrict__ Wd, const float* __restrict__ Sg,
    const float* __restrict__ Su, const float* __restrict__ Sd,
    const float* __restrict__ x, const float* __restrict__ Wr,
    unsigned short* __restrict__ WguT, unsigned short* __restrict__ WdT,
    unsigned short* __restrict__ SguT, unsigned short* __restrict__ SdT,
    unsigned short* __restrict__ Xb, float* __restrict__ logits) {
  const int z = blockIdx.z;
  const int tid = threadIdx.x;

  if (z == 22) {  // ---- router logits: 8 tokens per block ----
    const int bid = blockIdx.y * 16 + blockIdx.x;   // 0..255
    const int wave = tid >> 6;
    const int lane = tid & 63;
#pragma unroll
    for (int it = 0; it < 2; it++) {
      const int t = bid * 8 + wave * 2 + it;
      const float* xr = x + (size_t)t * 1024;
      float acc[8];
#pragma unroll
      for (int e = 0; e < 8; e++) acc[e] = 0.f;
#pragma unroll
      for (int i = 0; i < 16; i++) {
        int d = lane + i * 64;
        float xv = xr[d];
        const float4* w = (const float4*)(Wr + d * 8);
        float4 w0 = w[0], w1 = w[1];
        acc[0] += xv * w0.x; acc[1] += xv * w0.y; acc[2] += xv * w0.z; acc[3] += xv * w0.w;
        acc[4] += xv * w1.x; acc[5] += xv * w1.y; acc[6] += xv * w1.z; acc[7] += xv * w1.w;
      }
#pragma unroll
      for (int off = 32; off > 0; off >>= 1)
#pragma unroll
        for (int e = 0; e < 8; e++) acc[e] += __shfl_down(acc[e], off);
      if (lane == 0) {
#pragma unroll
        for (int e = 0; e < 8; e++) logits[t * 8 + e] = acc[e];
      }
    }
    return;
  }

  if (z >= 18) {  // ---- copy-cast x (row-major bf16) ----
    size_t off = (size_t)(z - 18) * 524288 + blockIdx.y * 32768 + blockIdx.x * 2048 + tid * 8;
    const float4* s = (const float4*)(x + off);
    float4 a = s[0], b = s[1];
    bf16x8 o = { (short)f2bf(a.x), (short)f2bf(a.y), (short)f2bf(a.z), (short)f2bf(a.w),
                 (short)f2bf(b.x), (short)f2bf(b.y), (short)f2bf(b.z), (short)f2bf(b.w) };
    *(bf16x8*)(Xb + off) = o;
    return;
  }

  __shared__ float tg[64][65];
  __shared__ float tu[64][65];

  if (z < 8 || z == 16) {  // ---- fused gate/up planes ----
    const float* sg_; const float* su_; unsigned short* base; int C;
    if (z < 8) { sg_ = Wg + (size_t)z * 524288; su_ = Wu + (size_t)z * 524288;
                 base = WguT + (size_t)z * 1048576; C = 512; }
    else       { sg_ = Sg; su_ = Su; base = SguT; C = 1024; }
    const int c0 = blockIdx.x * 64, r0 = blockIdx.y * 64;
    if (c0 >= C) return;
    {
      const int row = tid >> 2, cs = (tid & 3) * 16;
      const float* spg = sg_ + (size_t)(r0 + row) * C + c0 + cs;
      const float* spu = su_ + (size_t)(r0 + row) * C + c0 + cs;
#pragma unroll
      for (int k = 0; k < 4; k++) {
        float4 v = ((const float4*)spg)[k];
        tg[row][cs + k * 4 + 0] = v.x; tg[row][cs + k * 4 + 1] = v.y;
        tg[row][cs + k * 4 + 2] = v.z; tg[row][cs + k * 4 + 3] = v.w;
      }
#pragma unroll
      for (int k = 0; k < 4; k++) {
        float4 v = ((const float4*)spu)[k];
        tu[row][cs + k * 4 + 0] = v.x; tu[row][cs + k * 4 + 1] = v.y;
        tu[row][cs + k * 4 + 2] = v.z; tu[row][cs + k * 4 + 3] = v.w;
      }
    }
    __syncthreads();
#pragma unroll
    for (int i = 0; i < 2; i++) {
      const int cc = i * 32 + (tid >> 3);
      const int rseg = (tid & 7) * 8;
      bf16x8 og, ou;
#pragma unroll
      for (int j = 0; j < 8; j++) {
        og[j] = (short)f2bf(tg[rseg + j][cc]);
        ou[j] = (short)f2bf(tu[rseg + j][cc]);
      }
      const int f = c0 + cc;              // gate row 2f, up row 2f+1
      const int k0 = r0 + rseg;
      const int p = f >> 6;               // = (2f)>>7
      const int rg = (2 * f) & 127;
      const int s = k0 >> 5;
      const int c4 = ((k0 >> 3) & 3) ^ (f & 3);   // key (rg>>1)&3 == (ru>>1)&3 == f&3
      unsigned short* d = base + (size_t)p * 131072 + (size_t)s * 4096 + (rg * 4 + c4) * 8;
      *(bf16x8*)d = og;
      *(bf16x8*)(d + 32) = ou;            // slot +4 = 64B -> dense 128B lines
    }
    return;
  }

  // ---- unfused planes: Wd (z 8..15, R=512) / Sd (z 17) ----
  const float* src; unsigned short* base; int R, Ksz;
  if (z < 16) { src = Wd + (size_t)(z - 8) * 524288; base = WdT + (size_t)(z - 8) * 524288; R = 512; Ksz = 512; }
  else        { src = Sd; base = SdT; R = 1024; Ksz = 1024; }
  const int C = 1024;
  const int c0 = blockIdx.x * 64, r0 = blockIdx.y * 64;
  if (r0 >= R) return;
  {
    const int row = tid >> 2, cs = (tid & 3) * 16;
    const float* sp = src + (size_t)(r0 + row) * C + c0 + cs;
#pragma unroll
    for (int k = 0; k < 4; k++) {
      float4 v = ((const float4*)sp)[k];
      tg[row][cs + k * 4 + 0] = v.x; tg[row][cs + k * 4 + 1] = v.y;
      tg[row][cs + k * 4 + 2] = v.z; tg[row][cs + k * 4 + 3] = v.w;
    }
  }
  __syncthreads();
#pragma unroll
  for (int i = 0; i < 2; i++) {
    const int cc = i * 32 + (tid >> 3);
    const int rseg = (tid & 7) * 8;
    bf16x8 o;
#pragma unroll
    for (int j = 0; j < 8; j++) o[j] = (short)f2bf(tg[rseg + j][cc]);
    const int n = c0 + cc;
    const int k0 = r0 + rseg;
    const int p = n >> 7, r = n & 127, s = k0 >> 5;
    const int c4 = ((k0 >> 3) & 3) ^ ((r >> 1) & 3);
    *(bf16x8*)(base + (size_t)p * (Ksz * 128) + (size_t)s * 4096 + (r * 4 + c4) * 8) = o;
  }
}

// ---------------- router: assignment ----------------
__global__ __launch_bounds__(1024) void assign_kernel(
    const float* __restrict__ logits, const float* __restrict__ bias,
    int* __restrict__ list, int* __restrict__ ridx, float* __restrict__ rp,
    int* __restrict__ counts_g, int* __restrict__ offs_g) {
  __shared__ int cnt[8];
  __shared__ int offs[9];
  const int tid = threadIdx.x;
  if (tid < 8) cnt[tid] = 0;
  __syncthreads();
  int te[2][2], tpos[2][2];
  float tp[2][2];
#pragma unroll
  for (int it = 0; it < 2; it++) {
    int t = tid + it * 1024;
    float v[8];
#pragma unroll
    for (int e = 0; e < 8; e++) v[e] = logits[t * 8 + e] + bias[e];
    int i0 = 0;
#pragma unroll
    for (int e = 1; e < 8; e++) if (v[e] > v[i0]) i0 = e;
    int i1 = (i0 == 0) ? 1 : 0;
#pragma unroll
    for (int e = 0; e < 8; e++) if (e != i0 && v[e] > v[i1]) i1 = e;
    float pa = 1.f / (1.f + __expf(v[i1] - v[i0]));
    te[it][0] = i0; te[it][1] = i1;
    tp[it][0] = pa; tp[it][1] = 1.f - pa;
    tpos[it][0] = atomicAdd(&cnt[i0], 1);
    tpos[it][1] = atomicAdd(&cnt[i1], 1);
  }
  __syncthreads();
  if (tid == 0) {
    int s = 0;
#pragma unroll
    for (int e = 0; e < 8; e++) { offs[e] = s; s += cnt[e]; }
    offs[8] = s;
#pragma unroll
    for (int e = 0; e < 8; e++) { counts_g[e] = cnt[e]; offs_g[e] = offs[e]; }
    offs_g[8] = s;
  }
  __syncthreads();
#pragma unroll
  for (int it = 0; it < 2; it++) {
    int t = tid + it * 1024;
#pragma unroll
    for (int k = 0; k < 2; k++) {
      int grow = offs[te[it][k]] + tpos[it][k];
      list[grow] = t;
      ridx[t * 2 + k] = grow;
      rp[t * 2 + k] = tp[it][k];
    }
  }
}

// ---------------- BK=32, 3-buffer, depth-2 K-loop; 256x128 tile (6 gll16/thread/stage) ----------------
// A buffer 16KB (8192 shorts), B buffer 8KB (4096 shorts). Per thread per stage:
// 4 A gll16 (rows wave*64 + j*16 + (lane>>2), swizzled chunk) + 2 B gll16.
#define STAGE6(buf, s) { \
  unsigned short* Ad = As + (buf) * 8192 + wave * 2048; \
  unsigned short* Bd = Bs + (buf) * 4096 + wave * 1024; \
  gll16(gA0 + (s) * 32, Ad); \
  gll16(gA1 + (s) * 32, Ad + 512); \
  gll16(gA2 + (s) * 32, Ad + 1024); \
  gll16(gA3 + (s) * 32, Ad + 1536); \
  gll16(gB + (s) * 4096, Bd); \
  gll16(gB + (s) * 4096 + 512, Bd + 512); }

template <int NK>
__device__ __forceinline__ void kloop32(
    const unsigned short* gA0, const unsigned short* gA1,
    const unsigned short* gA2, const unsigned short* gA3,
    const unsigned short* gB,
    unsigned short* As, unsigned short* Bs, const int wave,
    const int aOb, const int bOb,
    f32x4 (&acc)[8][4]) {
  STAGE6(0, 0);
  STAGE6(1, 1);
#pragma unroll
  for (int i = 0; i < NK; ++i) {
    if (i + 1 < NK) asm volatile("s_waitcnt vmcnt(6) lgkmcnt(0)\n\ts_barrier" ::: "memory");
    else            asm volatile("s_waitcnt vmcnt(0) lgkmcnt(0)\n\ts_barrier" ::: "memory");
    if (i + 2 < NK) { STAGE6((i + 2) % 3, i + 2); }
    const unsigned short* Ab = As + (i % 3) * 8192;
    const unsigned short* Bb = Bs + (i % 3) * 4096;
    bf16x8 af[8], bf[4];
#pragma unroll
    for (int fi = 0; fi < 8; ++fi) af[fi] = *(const bf16x8*)(Ab + aOb + fi * 512);
#pragma unroll
    for (int fj = 0; fj < 4; ++fj) bf[fj] = *(const bf16x8*)(Bb + bOb + fj * 512);
    __builtin_amdgcn_s_setprio(1);
#pragma unroll
    for (int fi = 0; fi < 8; ++fi)
#pragma unroll
      for (int fj = 0; fj < 4; ++fj)
        acc[fi][fj] = __builtin_amdgcn_mfma_f32_16x16x32_bf16(af[fi], bf[fj], acc[fi][fj], 0, 0, 0);
    __builtin_amdgcn_s_setprio(0);
  }
}

// ---------------- fused TN GEMM: 256x128 tile, 4 waves of 128x64, XCD-class remap ----------------
template <int MODE>
__global__ __launch_bounds__(256, 2) void gemm_tn_kernel(
    const unsigned short* __restrict__ Xb, const unsigned short* __restrict__ He,
    const unsigned short* __restrict__ Hs, const unsigned short* __restrict__ Wgu,
    const unsigned short* __restrict__ Sgu, const unsigned short* __restrict__ Wd,
    const unsigned short* __restrict__ Sd, unsigned short* __restrict__ HeOut,
    unsigned short* __restrict__ HsOut, float* __restrict__ De, float* __restrict__ Ds,
    const int* __restrict__ list, const int* __restrict__ counts,
    const int* __restrict__ offs) {
  const int h = blockIdx.x;
  const int c = h & 7;
  const int idx = h >> 3;

  int cnt, lda, m0, n0;
  bool routed;
  const unsigned short* A;
  const unsigned short* Bt;
  const int* alist = nullptr;
  unsigned short* H = nullptr;
  float* D = nullptr;
  int ldh = 0;

  if (MODE == 0) {
    if (idx < 64) {
      routed = true;
      n0 = (idx >> 3) * 128; m0 = (idx & 7) * 256;
      cnt = counts[c]; A = Xb; alist = list + offs[c]; lda = 1024;
      Bt = Wgu + (size_t)c * 1048576 + (size_t)(n0 >> 7) * 131072;
      H = HeOut + (size_t)offs[c] * 512; ldh = 512;
    } else {
      routed = false;
      const int t2 = idx - 64;                        // 0..15
      m0 = ((c & 1) * 4 + (t2 & 3)) * 256;
      n0 = ((c >> 1) * 4 + (t2 >> 2)) * 128;
      cnt = 2048; A = Xb; lda = 1024;
      Bt = Sgu + (size_t)(n0 >> 7) * 131072;
      H = HsOut; ldh = 1024;
    }
  } else {
    if (idx < 64) {
      routed = true;
      n0 = (idx >> 3) * 128; m0 = (idx & 7) * 256;
      cnt = counts[c]; A = He + (size_t)offs[c] * 512; lda = 512;
      Bt = Wd + (size_t)c * 524288 + (size_t)(n0 >> 7) * 65536;
      D = De + (size_t)offs[c] * 1024;
    } else {
      routed = false;
      const int t2 = idx - 64;                        // 0..7
      m0 = ((c & 1) * 4 + (t2 & 3)) * 256;
      n0 = ((c >> 1) * 2 + (t2 >> 2)) * 128;
      cnt = 2048; A = Hs; lda = 1024;
      Bt = Sd + (size_t)(n0 >> 7) * 131072;
      D = Ds;
    }
  }
  if (m0 >= cnt) return;

  __shared__ unsigned short As[3 * 8192];   // 3 x 16 KB
  __shared__ unsigned short Bs[3 * 4096];   // 3 x 8 KB   (72 KB total -> 2 blocks/CU)

  const int tid = threadIdx.x;
  const int wave = tid >> 6;
  const int lane = tid & 63;

  // A staging: gll j covers rows wave*64 + j*16 + (lane>>2); storage chunk lane&3,
  // source data chunk (lane&3)^key, key = (row>>1)&3 = (lane>>3)&3.
  const int achk = ((lane & 3) ^ ((lane >> 3) & 3)) * 8;
  const int arow = wave * 64 + (lane >> 2);

  int r0 = m0 + arow;      if (r0 >= cnt) r0 = cnt - 1;
  int r1 = r0 - (m0 + arow) + m0 + arow + 16; r1 = m0 + arow + 16; if (r1 >= cnt) r1 = cnt - 1;
  int r2 = m0 + arow + 32; if (r2 >= cnt) r2 = cnt - 1;
  int r3 = m0 + arow + 48; if (r3 >= cnt) r3 = cnt - 1;
  size_t ab0, ab1, ab2, ab3;
  if (MODE == 0 && routed) {
    ab0 = (size_t)alist[r0] * lda; ab1 = (size_t)alist[r1] * lda;
    ab2 = (size_t)alist[r2] * lda; ab3 = (size_t)alist[r3] * lda;
  } else {
    ab0 = (size_t)r0 * lda; ab1 = (size_t)r1 * lda;
    ab2 = (size_t)r2 * lda; ab3 = (size_t)r3 * lda;
  }
  const unsigned short* gA0 = A + ab0 + achk;
  const unsigned short* gA1 = A + ab1 + achk;
  const unsigned short* gA2 = A + ab2 + achk;
  const unsigned short* gA3 = A + ab3 + achk;
  const unsigned short* gB = Bt + (wave * 128 + lane) * 8;

  const int wm = (wave & 1) * 128;          // wave-tile 128x64
  const int wn = (wave >> 1) * 64;
  const int fl = lane & 15;
  const int q = lane >> 4;

  const int cr = (q ^ ((fl >> 1) & 3)) * 8;
  const int aOb = (wm + fl) * 32 + cr;      // + fi*512 for fi=0..7
  const int bOb = (wn + fl) * 32 + cr;      // + fj*512 for fj=0..3

  f32x4 acc[8][4];
  f32x4 zero = {0.f, 0.f, 0.f, 0.f};
#pragma unroll
  for (int i = 0; i < 8; i++)
#pragma unroll
    for (int j = 0; j < 4; j++) acc[i][j] = zero;

  if (MODE == 1 && routed)
    kloop32<16>(gA0, gA1, gA2, gA3, gB, As, Bs, wave, aOb, bOb, acc);
  else
    kloop32<32>(gA0, gA1, gA2, gA3, gB, As, Bs, wave, aOb, bOb, acc);

  if (MODE == 0) {
#pragma unroll
    for (int fi = 0; fi < 8; fi++) {
#pragma unroll
      for (int fj = 0; fj < 4; fj++) {
#pragma unroll
        for (int r = 0; r < 4; r++) {
          int grow = m0 + wm + fi * 16 + q * 4 + r;
          float v = acc[fi][fj][r];
          float pv = __shfl_xor(v, 1);
          if ((lane & 1) == 0 && grow < cnt) {
            float s = v / (1.f + __expf(-v));
            int colh = (n0 + wn + fj * 16 + fl) >> 1;
            H[(size_t)grow * ldh + colh] = f2bf(s * pv);
          }
        }
      }
    }
  } else {
#pragma unroll
    for (int fi = 0; fi < 8; fi++) {
#pragma unroll
      for (int r = 0; r < 4; r++) {
        int grow = m0 + wm + fi * 16 + q * 4 + r;
        if (grow >= cnt) continue;
#pragma unroll
        for (int fj = 0; fj < 4; fj++) {
          int col = n0 + wn + fj * 16 + fl;
          D[(size_t)grow * 1024 + col] = acc[fi][fj][r];
        }
      }
    }
  }
}

// ---------------- combine ----------------
__global__ __launch_bounds__(256) void combine_kernel(
    const float* __restrict__ Ds, const float* __restrict__ De,
    const int* __restrict__ ridx, const float* __restrict__ rp,
    float* __restrict__ out) {
  const int t = blockIdx.x;
  const int i0 = ridx[t * 2], i1 = ridx[t * 2 + 1];
  const float p0 = rp[t * 2], p1 = rp[t * 2 + 1];
  const float4* a  = (const float4*)(Ds + (size_t)t * 1024);
  const float4* b0 = (const float4*)(De + (size_t)i0 * 1024);
  const float4* b1 = (const float4*)(De + (size_t)i1 * 1024);
  float4* o = (float4*)(out + (size_t)t * 1024);
  int c = threadIdx.x;
  float4 va = a[c], v0 = b0[c], v1 = b1[c];
  float4 r;
  r.x = va.x + p0 * v0.x + p1 * v1.x;
  r.y = va.y + p0 * v0.y + p1 * v1.y;
  r.z = va.z + p0 * v0.z + p1 * v1.z;
  r.w = va.w + p0 * v0.w + p1 * v1.w;
  o[c] = r;
}

// ---------------- launch ----------------
extern "C" void kernel_launch(void* const* d_in, const int* in_sizes, int n_in,
                              void* d_out, int out_size, void* d_ws, size_t ws_size,
                              hipStream_t stream) {
  const float* x    = (const float*)d_in[0];
  const float* Wr   = (const float*)d_in[1];
  const float* Wg   = (const float*)d_in[2];
  const float* Wu   = (const float*)d_in[3];
  const float* Wd   = (const float*)d_in[4];
  const float* Sg   = (const float*)d_in[5];
  const float* Su   = (const float*)d_in[6];
  const float* Sd   = (const float*)d_in[7];
  const float* bias = (const float*)d_in[8];
  float* out = (float*)d_out;

  char* ws = (char*)d_ws;
  size_t o = 0;
  auto alloc = [&](size_t b) { char* p = ws + o; o += (b + 255) & ~(size_t)255; return p; };
  unsigned short* Xb   = (unsigned short*)alloc((size_t)2048 * 1024 * 2);
  unsigned short* WguT = (unsigned short*)alloc((size_t)8 * 1024 * 1024 * 2);
  unsigned short* WdT  = (unsigned short*)alloc((size_t)8 * 1024 * 512 * 2);
  unsigned short* SguT = (unsigned short*)alloc((size_t)2048 * 1024 * 2);
  unsigned short* SdT  = (unsigned short*)alloc((size_t)1024 * 1024 * 2);
  float* logits = (float*)alloc((size_t)2048 * 8 * 4);
  int*   list   = (int*)alloc((size_t)4096 * 4);
  int*   ridx   = (int*)alloc((size_t)2048 * 2 * 4);
  float* rp     = (float*)alloc((size_t)2048 * 2 * 4);
  int*   counts = (int*)alloc(64);
  int*   offs   = (int*)alloc(64);
  unsigned short* He = (unsigned short*)alloc((size_t)4096 * 512 * 2);
  unsigned short* Hs = (unsigned short*)alloc((size_t)2048 * 1024 * 2);
  float* De = (float*)alloc((size_t)4096 * 1024 * 4);
  float* Ds = (float*)alloc((size_t)2048 * 1024 * 4);

  transpose_cvt_all<<<dim3(16, 16, 23), 256, 0, stream>>>(Wg, Wu, Wd, Sg, Su, Sd, x, Wr,
                                                          WguT, WdT, SguT, SdT, Xb, logits);

  assign_kernel<<<1, 1024, 0, stream>>>(logits, bias, list, ridx, rp, counts, offs);

  gemm_tn_kernel<0><<<dim3(640), 256, 0, stream>>>(
      Xb, He, Hs, WguT, SguT, WdT, SdT, He, Hs, De, Ds, list, counts, offs);
  gemm_tn_kernel<1><<<dim3(576), 256, 0, stream>>>(
      Xb, He, Hs, WguT, SguT, WdT, SdT, He, Hs, De, Ds, list, counts, offs);

  combine_kernel<<<2048, 256, 0, stream>>>(Ds, De, ridx, rp, out);
}

// Round 12
// 195.409 us; speedup vs baseline: 1.3018x; 1.0747x over previous
//
#include <hip/hip_runtime.h>
#include <cstdint>
#include <cstddef>

typedef __attribute__((ext_vector_type(8))) short bf16x8;
typedef __attribute__((ext_vector_type(4))) float f32x4;

#define AS1 __attribute__((address_space(1)))
#define AS3 __attribute__((address_space(3)))

__device__ __forceinline__ unsigned short f2bf(float f) {
  union { float f; unsigned int u; } v; v.f = f;
  unsigned int r = v.u + 0x7fffu + ((v.u >> 16) & 1u);
  return (unsigned short)(r >> 16);
}

__device__ __forceinline__ void gll16(const unsigned short* g, unsigned short* l) {
  __builtin_amdgcn_global_load_lds((const AS1 void*)g, (AS3 void*)l, 16, 0, 0);
}

// ============================================================================
// Btile layout (BK=32 steps): per (n-panel p of 128 rows, k-step s of 32):
// 512 slots of 16B; slot = r*4 + c4 holds B[n0+r][s*32 + (c4 ^ ((r>>1)&3))*8 .. +8].
// Panel stride = K*128 shorts; step stride = 4096 shorts.
// Gate/up fusion: rows 2f (gate) and 2f+1 (up) share XOR key (f&3) -> same c4;
// their slots are 4 apart (64B), so one thread writing both makes lines dense.
// ============================================================================

// ---------------- weight transposes (tiled, gate/up fused) + x cast + router logits ----------------
// z 0..7: Wg[e]+Wu[e] -> WguT[e] (both parities); z 8..15: Wd[e] -> WdT[e] (K=512)
// z 16: Sg+Su -> SguT; z 17: Sd -> SdT; z 18..21: x -> Xb cast; z 22: logits
__global__ __launch_bounds__(256) void transpose_cvt_all(
    const float* __restrict__ Wg, const float* __restrict__ Wu,
    const float* __restrict__ Wd, const float* __restrict__ Sg,
    const float* __restrict__ Su, const float* __restrict__ Sd,
    const float* __restrict__ x, const float* __restrict__ Wr,
    unsigned short* __restrict__ WguT, unsigned short* __restrict__ WdT,
    unsigned short* __restrict__ SguT, unsigned short* __restrict__ SdT,
    unsigned short* __restrict__ Xb, float* __restrict__ logits) {
  const int z = blockIdx.z;
  const int tid = threadIdx.x;

  if (z == 22) {  // ---- router logits: 8 tokens per block ----
    const int bid = blockIdx.y * 16 + blockIdx.x;   // 0..255
    const int wave = tid >> 6;
    const int lane = tid & 63;
#pragma unroll
    for (int it = 0; it < 2; it++) {
      const int t = bid * 8 + wave * 2 + it;
      const float* xr = x + (size_t)t * 1024;
      float acc[8];
#pragma unroll
      for (int e = 0; e < 8; e++) acc[e] = 0.f;
#pragma unroll
      for (int i = 0; i < 16; i++) {
        int d = lane + i * 64;
        float xv = xr[d];
        const float4* w = (const float4*)(Wr + d * 8);
        float4 w0 = w[0], w1 = w[1];
        acc[0] += xv * w0.x; acc[1] += xv * w0.y; acc[2] += xv * w0.z; acc[3] += xv * w0.w;
        acc[4] += xv * w1.x; acc[5] += xv * w1.y; acc[6] += xv * w1.z; acc[7] += xv * w1.w;
      }
#pragma unroll
      for (int off = 32; off > 0; off >>= 1)
#pragma unroll
        for (int e = 0; e < 8; e++) acc[e] += __shfl_down(acc[e], off);
      if (lane == 0) {
#pragma unroll
        for (int e = 0; e < 8; e++) logits[t * 8 + e] = acc[e];
      }
    }
    return;
  }

  if (z >= 18) {  // ---- copy-cast x (row-major bf16) ----
    size_t off = (size_t)(z - 18) * 524288 + blockIdx.y * 32768 + blockIdx.x * 2048 + tid * 8;
    const float4* s = (const float4*)(x + off);
    float4 a = s[0], b = s[1];
    bf16x8 o = { (short)f2bf(a.x), (short)f2bf(a.y), (short)f2bf(a.z), (short)f2bf(a.w),
                 (short)f2bf(b.x), (short)f2bf(b.y), (short)f2bf(b.z), (short)f2bf(b.w) };
    *(bf16x8*)(Xb + off) = o;
    return;
  }

  __shared__ float tg[64][65];
  __shared__ float tu[64][65];

  if (z < 8 || z == 16) {  // ---- fused gate/up planes ----
    const float* sg_; const float* su_; unsigned short* base; int C;
    if (z < 8) { sg_ = Wg + (size_t)z * 524288; su_ = Wu + (size_t)z * 524288;
                 base = WguT + (size_t)z * 1048576; C = 512; }
    else       { sg_ = Sg; su_ = Su; base = SguT; C = 1024; }
    const int c0 = blockIdx.x * 64, r0 = blockIdx.y * 64;
    if (c0 >= C) return;
    {
      const int row = tid >> 2, cs = (tid & 3) * 16;
      const float* spg = sg_ + (size_t)(r0 + row) * C + c0 + cs;
      const float* spu = su_ + (size_t)(r0 + row) * C + c0 + cs;
#pragma unroll
      for (int k = 0; k < 4; k++) {
        float4 v = ((const float4*)spg)[k];
        tg[row][cs + k * 4 + 0] = v.x; tg[row][cs + k * 4 + 1] = v.y;
        tg[row][cs + k * 4 + 2] = v.z; tg[row][cs + k * 4 + 3] = v.w;
      }
#pragma unroll
      for (int k = 0; k < 4; k++) {
        float4 v = ((const float4*)spu)[k];
        tu[row][cs + k * 4 + 0] = v.x; tu[row][cs + k * 4 + 1] = v.y;
        tu[row][cs + k * 4 + 2] = v.z; tu[row][cs + k * 4 + 3] = v.w;
      }
    }
    __syncthreads();
#pragma unroll
    for (int i = 0; i < 2; i++) {
      const int cc = i * 32 + (tid >> 3);
      const int rseg = (tid & 7) * 8;
      bf16x8 og, ou;
#pragma unroll
      for (int j = 0; j < 8; j++) {
        og[j] = (short)f2bf(tg[rseg + j][cc]);
        ou[j] = (short)f2bf(tu[rseg + j][cc]);
      }
      const int f = c0 + cc;              // gate row 2f, up row 2f+1
      const int k0 = r0 + rseg;
      const int p = f >> 6;               // = (2f)>>7
      const int rg = (2 * f) & 127;
      const int s = k0 >> 5;
      const int c4 = ((k0 >> 3) & 3) ^ (f & 3);   // key (rg>>1)&3 == (ru>>1)&3 == f&3
      unsigned short* d = base + (size_t)p * 131072 + (size_t)s * 4096 + (rg * 4 + c4) * 8;
      *(bf16x8*)d = og;
      *(bf16x8*)(d + 32) = ou;            // slot +4 = 64B -> dense 128B lines
    }
    return;
  }

  // ---- unfused planes: Wd (z 8..15, R=512) / Sd (z 17) ----
  const float* src; unsigned short* base; int R, Ksz;
  if (z < 16) { src = Wd + (size_t)(z - 8) * 524288; base = WdT + (size_t)(z - 8) * 524288; R = 512; Ksz = 512; }
  else        { src = Sd; base = SdT; R = 1024; Ksz = 1024; }
  const int C = 1024;
  const int c0 = blockIdx.x * 64, r0 = blockIdx.y * 64;
  if (r0 >= R) return;
  {
    const int row = tid >> 2, cs = (tid & 3) * 16;
    const float* sp = src + (size_t)(r0 + row) * C + c0 + cs;
#pragma unroll
    for (int k = 0; k < 4; k++) {
      float4 v = ((const float4*)sp)[k];
      tg[row][cs + k * 4 + 0] = v.x; tg[row][cs + k * 4 + 1] = v.y;
      tg[row][cs + k * 4 + 2] = v.z; tg[row][cs + k * 4 + 3] = v.w;
    }
  }
  __syncthreads();
#pragma unroll
  for (int i = 0; i < 2; i++) {
    const int cc = i * 32 + (tid >> 3);
    const int rseg = (tid & 7) * 8;
    bf16x8 o;
#pragma unroll
    for (int j = 0; j < 8; j++) o[j] = (short)f2bf(tg[rseg + j][cc]);
    const int n = c0 + cc;
    const int k0 = r0 + rseg;
    const int p = n >> 7, r = n & 127, s = k0 >> 5;
    const int c4 = ((k0 >> 3) & 3) ^ ((r >> 1) & 3);
    *(bf16x8*)(base + (size_t)p * (Ksz * 128) + (size_t)s * 4096 + (r * 4 + c4) * 8) = o;
  }
}

// ---------------- router: assignment ----------------
__global__ __launch_bounds__(1024) void assign_kernel(
    const float* __restrict__ logits, const float* __restrict__ bias,
    int* __restrict__ list, int* __restrict__ ridx, float* __restrict__ rp,
    int* __restrict__ counts_g, int* __restrict__ offs_g) {
  __shared__ int cnt[8];
  __shared__ int offs[9];
  const int tid = threadIdx.x;
  if (tid < 8) cnt[tid] = 0;
  __syncthreads();
  int te[2][2], tpos[2][2];
  float tp[2][2];
#pragma unroll
  for (int it = 0; it < 2; it++) {
    int t = tid + it * 1024;
    float v[8];
#pragma unroll
    for (int e = 0; e < 8; e++) v[e] = logits[t * 8 + e] + bias[e];
    int i0 = 0;
#pragma unroll
    for (int e = 1; e < 8; e++) if (v[e] > v[i0]) i0 = e;
    int i1 = (i0 == 0) ? 1 : 0;
#pragma unroll
    for (int e = 0; e < 8; e++) if (e != i0 && v[e] > v[i1]) i1 = e;
    float pa = 1.f / (1.f + __expf(v[i1] - v[i0]));
    te[it][0] = i0; te[it][1] = i1;
    tp[it][0] = pa; tp[it][1] = 1.f - pa;
    tpos[it][0] = atomicAdd(&cnt[i0], 1);
    tpos[it][1] = atomicAdd(&cnt[i1], 1);
  }
  __syncthreads();
  if (tid == 0) {
    int s = 0;
#pragma unroll
    for (int e = 0; e < 8; e++) { offs[e] = s; s += cnt[e]; }
    offs[8] = s;
#pragma unroll
    for (int e = 0; e < 8; e++) { counts_g[e] = cnt[e]; offs_g[e] = offs[e]; }
    offs_g[8] = s;
  }
  __syncthreads();
#pragma unroll
  for (int it = 0; it < 2; it++) {
    int t = tid + it * 1024;
#pragma unroll
    for (int k = 0; k < 2; k++) {
      int grow = offs[te[it][k]] + tpos[it][k];
      list[grow] = t;
      ridx[t * 2 + k] = grow;
      rp[t * 2 + k] = tp[it][k];
    }
  }
}

// ---------------- BK=32, 3-buffer, depth-2 prefetch K-loop (proven best) ----------------
#define STAGE4(buf, s) { \
  unsigned short* Ad = As + (buf) * 4096 + wuni2; \
  unsigned short* Bd = Bs + (buf) * 4096 + wuni2; \
  gll16(gA0 + (s) * 32, Ad); \
  gll16(gA1 + (s) * 32, Ad + 512); \
  gll16(gB + (s) * 4096, Bd); \
  gll16(gB + (s) * 4096 + 512, Bd + 512); }

template <int NK>
__device__ __forceinline__ void kloop32(
    const unsigned short* gA0, const unsigned short* gA1,
    const unsigned short* gB,
    unsigned short* As, unsigned short* Bs, const int wuni2,
    const int aO0, const int aO1, const int aO2, const int aO3,
    const int bO0, const int bO1, const int bO2, const int bO3,
    f32x4 (&acc)[4][4]) {
  STAGE4(0, 0);
  STAGE4(1, 1);
#pragma unroll
  for (int i = 0; i < NK; ++i) {
    if (i + 1 < NK) asm volatile("s_waitcnt vmcnt(4) lgkmcnt(0)\n\ts_barrier" ::: "memory");
    else            asm volatile("s_waitcnt vmcnt(0) lgkmcnt(0)\n\ts_barrier" ::: "memory");
    if (i + 2 < NK) { STAGE4((i + 2) % 3, i + 2); }
    const unsigned short* Ab = As + (i % 3) * 4096;
    const unsigned short* Bb = Bs + (i % 3) * 4096;
    bf16x8 af[4], bf[4];
    af[0] = *(const bf16x8*)(Ab + aO0);
    af[1] = *(const bf16x8*)(Ab + aO1);
    af[2] = *(const bf16x8*)(Ab + aO2);
    af[3] = *(const bf16x8*)(Ab + aO3);
    bf[0] = *(const bf16x8*)(Bb + bO0);
    bf[1] = *(const bf16x8*)(Bb + bO1);
    bf[2] = *(const bf16x8*)(Bb + bO2);
    bf[3] = *(const bf16x8*)(Bb + bO3);
    __builtin_amdgcn_s_setprio(1);
#pragma unroll
    for (int ii = 0; ii < 4; ++ii)
#pragma unroll
      for (int jj = 0; jj < 4; ++jj)
        acc[ii][jj] = __builtin_amdgcn_mfma_f32_16x16x32_bf16(af[ii], bf[jj], acc[ii][jj], 0, 0, 0);
    __builtin_amdgcn_s_setprio(0);
  }
}

// ---------------- fused TN GEMM: 128x128 tile, 4 waves, BK=32, XCD-class remap ----------------
template <int MODE>
__global__ __launch_bounds__(256, 3) void gemm_tn_kernel(
    const unsigned short* __restrict__ Xb, const unsigned short* __restrict__ He,
    const unsigned short* __restrict__ Hs, const unsigned short* __restrict__ Wgu,
    const unsigned short* __restrict__ Sgu, const unsigned short* __restrict__ Wd,
    const unsigned short* __restrict__ Sd, unsigned short* __restrict__ HeOut,
    unsigned short* __restrict__ HsOut, float* __restrict__ De, float* __restrict__ Ds,
    const int* __restrict__ list, const int* __restrict__ counts,
    const int* __restrict__ offs) {
  const int h = blockIdx.x;
  const int c = h & 7;
  const int idx = h >> 3;

  int cnt, lda, m0, n0;
  bool routed;
  const unsigned short* A;
  const unsigned short* Bt;
  const int* alist = nullptr;
  unsigned short* H = nullptr;
  float* D = nullptr;
  int ldh = 0;

  if (MODE == 0) {
    if (idx < 128) {
      routed = true;
      n0 = (idx >> 4) * 128; m0 = (idx & 15) * 128;
      cnt = counts[c]; A = Xb; alist = list + offs[c]; lda = 1024;
      Bt = Wgu + (size_t)c * 1048576 + (size_t)(n0 >> 7) * 131072;
      H = HeOut + (size_t)offs[c] * 512; ldh = 512;
    } else {
      routed = false;
      const int t2 = idx - 128;                       // 0..31
      m0 = ((c & 1) * 8 + (t2 & 7)) * 128;
      n0 = ((c >> 1) * 4 + (t2 >> 3)) * 128;
      cnt = 2048; A = Xb; lda = 1024;
      Bt = Sgu + (size_t)(n0 >> 7) * 131072;
      H = HsOut; ldh = 1024;
    }
  } else {
    if (idx < 128) {
      routed = true;
      n0 = (idx >> 4) * 128; m0 = (idx & 15) * 128;
      cnt = counts[c]; A = He + (size_t)offs[c] * 512; lda = 512;
      Bt = Wd + (size_t)c * 524288 + (size_t)(n0 >> 7) * 65536;
      D = De + (size_t)offs[c] * 1024;
    } else {
      routed = false;
      const int t2 = idx - 128;                       // 0..15
      m0 = ((c & 1) * 8 + (t2 & 7)) * 128;
      n0 = ((c >> 1) * 2 + (t2 >> 3)) * 128;
      cnt = 2048; A = Hs; lda = 1024;
      Bt = Sd + (size_t)(n0 >> 7) * 131072;
      D = Ds;
    }
  }
  if (m0 >= cnt) return;

  __shared__ unsigned short As[3 * 4096];   // 3 x 8 KB
  __shared__ unsigned short Bs[3 * 4096];   // 3 x 8 KB

  const int tid = threadIdx.x;
  const int wave = tid >> 6;
  const int lane = tid & 63;
  const int wuni2 = wave * 1024;

  const int achk = ((lane & 3) ^ ((lane >> 3) & 3)) * 8;
  const int arow0 = wave * 32 + (lane >> 2);
  const int arow1 = arow0 + 16;

  int r0 = m0 + arow0; if (r0 >= cnt) r0 = cnt - 1;
  int r1 = m0 + arow1; if (r1 >= cnt) r1 = cnt - 1;
  size_t ab0, ab1;
  if (MODE == 0 && routed) {
    ab0 = (size_t)alist[r0] * lda; ab1 = (size_t)alist[r1] * lda;
  } else {
    ab0 = (size_t)r0 * lda; ab1 = (size_t)r1 * lda;
  }
  const unsigned short* gA0 = A + ab0 + achk;
  const unsigned short* gA1 = A + ab1 + achk;
  const unsigned short* gB = Bt + (wave * 128 + lane) * 8;

  const int wm = (wave & 1) * 64;
  const int wn = (wave >> 1) * 64;
  const int fl = lane & 15;
  const int q = lane >> 4;

  const int cr = (q ^ ((fl >> 1) & 3)) * 8;
  const int aO0 = (wm + fl) * 32 + cr, aO1 = aO0 + 512, aO2 = aO0 + 1024, aO3 = aO0 + 1536;
  const int bO0 = (wn + fl) * 32 + cr, bO1 = bO0 + 512, bO2 = bO0 + 1024, bO3 = bO0 + 1536;

  f32x4 acc[4][4];
  f32x4 zero = {0.f, 0.f, 0.f, 0.f};
#pragma unroll
  for (int i = 0; i < 4; i++)
#pragma unroll
    for (int j = 0; j < 4; j++) acc[i][j] = zero;

  if (MODE == 1 && routed)
    kloop32<16>(gA0, gA1, gB, As, Bs, wuni2, aO0, aO1, aO2, aO3, bO0, bO1, bO2, bO3, acc);
  else
    kloop32<32>(gA0, gA1, gB, As, Bs, wuni2, aO0, aO1, aO2, aO3, bO0, bO1, bO2, bO3, acc);

  if (MODE == 0) {
#pragma unroll
    for (int i = 0; i < 4; i++) {
#pragma unroll
      for (int j = 0; j < 4; j++) {
#pragma unroll
        for (int r = 0; r < 4; r++) {
          int grow = m0 + wm + i * 16 + q * 4 + r;
          float v = acc[i][j][r];
          float pv = __shfl_xor(v, 1);
          if ((lane & 1) == 0 && grow < cnt) {
            float s = v / (1.f + __expf(-v));
            int colh = (n0 + wn + j * 16 + fl) >> 1;
            H[(size_t)grow * ldh + colh] = f2bf(s * pv);
          }
        }
      }
    }
  } else {
#pragma unroll
    for (int i = 0; i < 4; i++) {
#pragma unroll
      for (int r = 0; r < 4; r++) {
        int grow = m0 + wm + i * 16 + q * 4 + r;
        if (grow >= cnt) continue;
#pragma unroll
        for (int j = 0; j < 4; j++) {
          int col = n0 + wn + j * 16 + fl;
          D[(size_t)grow * 1024 + col] = acc[i][j][r];
        }
      }
    }
  }
}

// ---------------- combine ----------------
__global__ __launch_bounds__(256) void combine_kernel(
    const float* __restrict__ Ds, const float* __restrict__ De,
    const int* __restrict__ ridx, const float* __restrict__ rp,
    float* __restrict__ out) {
  const int t = blockIdx.x;
  const int i0 = ridx[t * 2], i1 = ridx[t * 2 + 1];
  const float p0 = rp[t * 2], p1 = rp[t * 2 + 1];
  const float4* a  = (const float4*)(Ds + (size_t)t * 1024);
  const float4* b0 = (const float4*)(De + (size_t)i0 * 1024);
  const float4* b1 = (const float4*)(De + (size_t)i1 * 1024);
  float4* o = (float4*)(out + (size_t)t * 1024);
  int c = threadIdx.x;
  float4 va = a[c], v0 = b0[c], v1 = b1[c];
  float4 r;
  r.x = va.x + p0 * v0.x + p1 * v1.x;
  r.y = va.y + p0 * v0.y + p1 * v1.y;
  r.z = va.z + p0 * v0.z + p1 * v1.z;
  r.w = va.w + p0 * v0.w + p1 * v1.w;
  o[c] = r;
}

// ---------------- launch ----------------
extern "C" void kernel_launch(void* const* d_in, const int* in_sizes, int n_in,
                              void* d_out, int out_size, void* d_ws, size_t ws_size,
                              hipStream_t stream) {
  const float* x    = (const float*)d_in[0];
  const float* Wr   = (const float*)d_in[1];
  const float* Wg   = (const float*)d_in[2];
  const float* Wu   = (const float*)d_in[3];
  const float* Wd   = (const float*)d_in[4];
  const float* Sg   = (const float*)d_in[5];
  const float* Su   = (const float*)d_in[6];
  const float* Sd   = (const float*)d_in[7];
  const float* bias = (const float*)d_in[8];
  float* out = (float*)d_out;

  char* ws = (char*)d_ws;
  size_t o = 0;
  auto alloc = [&](size_t b) { char* p = ws + o; o += (b + 255) & ~(size_t)255; return p; };
  unsigned short* Xb   = (unsigned short*)alloc((size_t)2048 * 1024 * 2);
  unsigned short* WguT = (unsigned short*)alloc((size_t)8 * 1024 * 1024 * 2);
  unsigned short* WdT  = (unsigned short*)alloc((size_t)8 * 1024 * 512 * 2);
  unsigned short* SguT = (unsigned short*)alloc((size_t)2048 * 1024 * 2);
  unsigned short* SdT  = (unsigned short*)alloc((size_t)1024 * 1024 * 2);
  float* logits = (float*)alloc((size_t)2048 * 8 * 4);
  int*   list   = (int*)alloc((size_t)4096 * 4);
  int*   ridx   = (int*)alloc((size_t)2048 * 2 * 4);
  float* rp     = (float*)alloc((size_t)2048 * 2 * 4);
  int*   counts = (int*)alloc(64);
  int*   offs   = (int*)alloc(64);
  unsigned short* He = (unsigned short*)alloc((size_t)4096 * 512 * 2);
  unsigned short* Hs = (unsigned short*)alloc((size_t)2048 * 1024 * 2);
  float* De = (float*)alloc((size_t)4096 * 1024 * 4);
  float* Ds = (float*)alloc((size_t)2048 * 1024 * 4);

  transpose_cvt_all<<<dim3(16, 16, 23), 256, 0, stream>>>(Wg, Wu, Wd, Sg, Su, Sd, x, Wr,
                                                          WguT, WdT, SguT, SdT, Xb, logits);

  assign_kernel<<<1, 1024, 0, stream>>>(logits, bias, list, ridx, rp, counts, offs);

  gemm_tn_kernel<0><<<dim3(1280), 256, 0, stream>>>(
      Xb, He, Hs, WguT, SguT, WdT, SdT, He, Hs, De, Ds, list, counts, offs);
  gemm_tn_kernel<1><<<dim3(1152), 256, 0, stream>>>(
      Xb, He, Hs, WguT, SguT, WdT, SdT, He, Hs, De, Ds, list, counts, offs);

  combine_kernel<<<2048, 256, 0, stream>>>(Ds, De, ridx, rp, out);
}

// Round 13
// 192.038 us; speedup vs baseline: 1.3246x; 1.0176x over previous
//
#include <hip/hip_runtime.h>
#include <cstdint>
#include <cstddef>

typedef __attribute__((ext_vector_type(8))) short bf16x8;
typedef __attribute__((ext_vector_type(4))) float f32x4;

#define AS1 __attribute__((address_space(1)))
#define AS3 __attribute__((address_space(3)))

__device__ __forceinline__ unsigned short f2bf(float f) {
  union { float f; unsigned int u; } v; v.f = f;
  unsigned int r = v.u + 0x7fffu + ((v.u >> 16) & 1u);
  return (unsigned short)(r >> 16);
}

__device__ __forceinline__ void gll16(const unsigned short* g, unsigned short* l) {
  __builtin_amdgcn_global_load_lds((const AS1 void*)g, (AS3 void*)l, 16, 0, 0);
}

// ============================================================================
// Btile layout (BK=32 steps): per (n-panel p of 128 rows, k-step s of 32):
// 512 slots of 16B; slot = r*4 + c4 holds B[n0+r][s*32 + (c4 ^ ((r>>1)&3))*8 .. +8].
// Panel stride = K*128 shorts; step stride = 4096 shorts.
// Gate/up fusion: rows 2f (gate) and 2f+1 (up) share XOR key (f&3) -> same c4;
// their slots are 4 apart (64B), so one thread writing both makes lines dense.
// ============================================================================

// ---------------- weight transposes (tiled, gate/up fused) + x cast + router logits ----------------
// z 0..7: Wg[e]+Wu[e] -> WguT[e] (both parities); z 8..15: Wd[e] -> WdT[e] (K=512)
// z 16: Sg+Su -> SguT; z 17: Sd -> SdT; z 18..21: x -> Xb cast; z 22: logits
__global__ __launch_bounds__(256) void transpose_cvt_all(
    const float* __restrict__ Wg, const float* __restrict__ Wu,
    const float* __restrict__ Wd, const float* __restrict__ Sg,
    const float* __restrict__ Su, const float* __restrict__ Sd,
    const float* __restrict__ x, const float* __restrict__ Wr,
    unsigned short* __restrict__ WguT, unsigned short* __restrict__ WdT,
    unsigned short* __restrict__ SguT, unsigned short* __restrict__ SdT,
    unsigned short* __restrict__ Xb, float* __restrict__ logits) {
  const int z = blockIdx.z;
  const int tid = threadIdx.x;

  if (z == 22) {  // ---- router logits: 8 tokens per block ----
    const int bid = blockIdx.y * 16 + blockIdx.x;   // 0..255
    const int wave = tid >> 6;
    const int lane = tid & 63;
#pragma unroll
    for (int it = 0; it < 2; it++) {
      const int t = bid * 8 + wave * 2 + it;
      const float* xr = x + (size_t)t * 1024;
      float acc[8];
#pragma unroll
      for (int e = 0; e < 8; e++) acc[e] = 0.f;
#pragma unroll
      for (int i = 0; i < 16; i++) {
        int d = lane + i * 64;
        float xv = xr[d];
        const float4* w = (const float4*)(Wr + d * 8);
        float4 w0 = w[0], w1 = w[1];
        acc[0] += xv * w0.x; acc[1] += xv * w0.y; acc[2] += xv * w0.z; acc[3] += xv * w0.w;
        acc[4] += xv * w1.x; acc[5] += xv * w1.y; acc[6] += xv * w1.z; acc[7] += xv * w1.w;
      }
#pragma unroll
      for (int off = 32; off > 0; off >>= 1)
#pragma unroll
        for (int e = 0; e < 8; e++) acc[e] += __shfl_down(acc[e], off);
      if (lane == 0) {
#pragma unroll
        for (int e = 0; e < 8; e++) logits[t * 8 + e] = acc[e];
      }
    }
    return;
  }

  if (z >= 18) {  // ---- copy-cast x (row-major bf16) ----
    size_t off = (size_t)(z - 18) * 524288 + blockIdx.y * 32768 + blockIdx.x * 2048 + tid * 8;
    const float4* s = (const float4*)(x + off);
    float4 a = s[0], b = s[1];
    bf16x8 o = { (short)f2bf(a.x), (short)f2bf(a.y), (short)f2bf(a.z), (short)f2bf(a.w),
                 (short)f2bf(b.x), (short)f2bf(b.y), (short)f2bf(b.z), (short)f2bf(b.w) };
    *(bf16x8*)(Xb + off) = o;
    return;
  }

  __shared__ float tg[64][65];
  __shared__ float tu[64][65];

  if (z < 8 || z == 16) {  // ---- fused gate/up planes ----
    const float* sg_; const float* su_; unsigned short* base; int C;
    if (z < 8) { sg_ = Wg + (size_t)z * 524288; su_ = Wu + (size_t)z * 524288;
                 base = WguT + (size_t)z * 1048576; C = 512; }
    else       { sg_ = Sg; su_ = Su; base = SguT; C = 1024; }
    const int c0 = blockIdx.x * 64, r0 = blockIdx.y * 64;
    if (c0 >= C) return;
    {
      const int row = tid >> 2, cs = (tid & 3) * 16;
      const float* spg = sg_ + (size_t)(r0 + row) * C + c0 + cs;
      const float* spu = su_ + (size_t)(r0 + row) * C + c0 + cs;
#pragma unroll
      for (int k = 0; k < 4; k++) {
        float4 v = ((const float4*)spg)[k];
        tg[row][cs + k * 4 + 0] = v.x; tg[row][cs + k * 4 + 1] = v.y;
        tg[row][cs + k * 4 + 2] = v.z; tg[row][cs + k * 4 + 3] = v.w;
      }
#pragma unroll
      for (int k = 0; k < 4; k++) {
        float4 v = ((const float4*)spu)[k];
        tu[row][cs + k * 4 + 0] = v.x; tu[row][cs + k * 4 + 1] = v.y;
        tu[row][cs + k * 4 + 2] = v.z; tu[row][cs + k * 4 + 3] = v.w;
      }
    }
    __syncthreads();
#pragma unroll
    for (int i = 0; i < 2; i++) {
      const int cc = i * 32 + (tid >> 3);
      const int rseg = (tid & 7) * 8;
      bf16x8 og, ou;
#pragma unroll
      for (int j = 0; j < 8; j++) {
        og[j] = (short)f2bf(tg[rseg + j][cc]);
        ou[j] = (short)f2bf(tu[rseg + j][cc]);
      }
      const int f = c0 + cc;              // gate row 2f, up row 2f+1
      const int k0 = r0 + rseg;
      const int p = f >> 6;               // = (2f)>>7
      const int rg = (2 * f) & 127;
      const int s = k0 >> 5;
      const int c4 = ((k0 >> 3) & 3) ^ (f & 3);   // key (rg>>1)&3 == (ru>>1)&3 == f&3
      unsigned short* d = base + (size_t)p * 131072 + (size_t)s * 4096 + (rg * 4 + c4) * 8;
      *(bf16x8*)d = og;
      *(bf16x8*)(d + 32) = ou;            // slot +4 = 64B -> dense 128B lines
    }
    return;
  }

  // ---- unfused planes: Wd (z 8..15, R=512) / Sd (z 17) ----
  const float* src; unsigned short* base; int R, Ksz;
  if (z < 16) { src = Wd + (size_t)(z - 8) * 524288; base = WdT + (size_t)(z - 8) * 524288; R = 512; Ksz = 512; }
  else        { src = Sd; base = SdT; R = 1024; Ksz = 1024; }
  const int C = 1024;
  const int c0 = blockIdx.x * 64, r0 = blockIdx.y * 64;
  if (r0 >= R) return;
  {
    const int row = tid >> 2, cs = (tid & 3) * 16;
    const float* sp = src + (size_t)(r0 + row) * C + c0 + cs;
#pragma unroll
    for (int k = 0; k < 4; k++) {
      float4 v = ((const float4*)sp)[k];
      tg[row][cs + k * 4 + 0] = v.x; tg[row][cs + k * 4 + 1] = v.y;
      tg[row][cs + k * 4 + 2] = v.z; tg[row][cs + k * 4 + 3] = v.w;
    }
  }
  __syncthreads();
#pragma unroll
  for (int i = 0; i < 2; i++) {
    const int cc = i * 32 + (tid >> 3);
    const int rseg = (tid & 7) * 8;
    bf16x8 o;
#pragma unroll
    for (int j = 0; j < 8; j++) o[j] = (short)f2bf(tg[rseg + j][cc]);
    const int n = c0 + cc;
    const int k0 = r0 + rseg;
    const int p = n >> 7, r = n & 127, s = k0 >> 5;
    const int c4 = ((k0 >> 3) & 3) ^ ((r >> 1) & 3);
    *(bf16x8*)(base + (size_t)p * (Ksz * 128) + (size_t)s * 4096 + (r * 4 + c4) * 8) = o;
  }
}

// ---------------- router: assignment ----------------
__global__ __launch_bounds__(1024) void assign_kernel(
    const float* __restrict__ logits, const float* __restrict__ bias,
    int* __restrict__ list, int* __restrict__ ridx, float* __restrict__ rp,
    int* __restrict__ counts_g, int* __restrict__ offs_g) {
  __shared__ int cnt[8];
  __shared__ int offs[9];
  const int tid = threadIdx.x;
  if (tid < 8) cnt[tid] = 0;
  __syncthreads();
  int te[2][2], tpos[2][2];
  float tp[2][2];
#pragma unroll
  for (int it = 0; it < 2; it++) {
    int t = tid + it * 1024;
    float v[8];
#pragma unroll
    for (int e = 0; e < 8; e++) v[e] = logits[t * 8 + e] + bias[e];
    int i0 = 0;
#pragma unroll
    for (int e = 1; e < 8; e++) if (v[e] > v[i0]) i0 = e;
    int i1 = (i0 == 0) ? 1 : 0;
#pragma unroll
    for (int e = 0; e < 8; e++) if (e != i0 && v[e] > v[i1]) i1 = e;
    float pa = 1.f / (1.f + __expf(v[i1] - v[i0]));
    te[it][0] = i0; te[it][1] = i1;
    tp[it][0] = pa; tp[it][1] = 1.f - pa;
    tpos[it][0] = atomicAdd(&cnt[i0], 1);
    tpos[it][1] = atomicAdd(&cnt[i1], 1);
  }
  __syncthreads();
  if (tid == 0) {
    int s = 0;
#pragma unroll
    for (int e = 0; e < 8; e++) { offs[e] = s; s += cnt[e]; }
    offs[8] = s;
#pragma unroll
    for (int e = 0; e < 8; e++) { counts_g[e] = cnt[e]; offs_g[e] = offs[e]; }
    offs_g[8] = s;
  }
  __syncthreads();
#pragma unroll
  for (int it = 0; it < 2; it++) {
    int t = tid + it * 1024;
#pragma unroll
    for (int k = 0; k < 2; k++) {
      int grow = offs[te[it][k]] + tpos[it][k];
      list[grow] = t;
      ridx[t * 2 + k] = grow;
      rp[t * 2 + k] = tp[it][k];
    }
  }
}

// ---------------- BK=32, 3-buffer, depth-2 prefetch K-loop (proven best) ----------------
#define STAGE4(buf, s) { \
  unsigned short* Ad = As + (buf) * 4096 + wuni2; \
  unsigned short* Bd = Bs + (buf) * 4096 + wuni2; \
  gll16(gA0 + (s) * 32, Ad); \
  gll16(gA1 + (s) * 32, Ad + 512); \
  gll16(gB + (s) * 4096, Bd); \
  gll16(gB + (s) * 4096 + 512, Bd + 512); }

template <int NK>
__device__ __forceinline__ void kloop32(
    const unsigned short* gA0, const unsigned short* gA1,
    const unsigned short* gB,
    unsigned short* As, unsigned short* Bs, const int wuni2,
    const int aO0, const int aO1, const int aO2, const int aO3,
    const int bO0, const int bO1, const int bO2, const int bO3,
    f32x4 (&acc)[4][4]) {
  STAGE4(0, 0);
  STAGE4(1, 1);
#pragma unroll
  for (int i = 0; i < NK; ++i) {
    if (i + 1 < NK) asm volatile("s_waitcnt vmcnt(4) lgkmcnt(0)\n\ts_barrier" ::: "memory");
    else            asm volatile("s_waitcnt vmcnt(0) lgkmcnt(0)\n\ts_barrier" ::: "memory");
    if (i + 2 < NK) { STAGE4((i + 2) % 3, i + 2); }
    const unsigned short* Ab = As + (i % 3) * 4096;
    const unsigned short* Bb = Bs + (i % 3) * 4096;
    bf16x8 af[4], bf[4];
    af[0] = *(const bf16x8*)(Ab + aO0);
    af[1] = *(const bf16x8*)(Ab + aO1);
    af[2] = *(const bf16x8*)(Ab + aO2);
    af[3] = *(const bf16x8*)(Ab + aO3);
    bf[0] = *(const bf16x8*)(Bb + bO0);
    bf[1] = *(const bf16x8*)(Bb + bO1);
    bf[2] = *(const bf16x8*)(Bb + bO2);
    bf[3] = *(const bf16x8*)(Bb + bO3);
    __builtin_amdgcn_s_setprio(1);
#pragma unroll
    for (int ii = 0; ii < 4; ++ii)
#pragma unroll
      for (int jj = 0; jj < 4; ++jj)
        acc[ii][jj] = __builtin_amdgcn_mfma_f32_16x16x32_bf16(af[ii], bf[jj], acc[ii][jj], 0, 0, 0);
    __builtin_amdgcn_s_setprio(0);
  }
}

// ---------------- fused TN GEMM: 128x128 tile, 4 waves, BK=32, XCD-class remap ----------------
template <int MODE>
__global__ __launch_bounds__(256, 3) void gemm_tn_kernel(
    const unsigned short* __restrict__ Xb, const unsigned short* __restrict__ He,
    const unsigned short* __restrict__ Hs, const unsigned short* __restrict__ Wgu,
    const unsigned short* __restrict__ Sgu, const unsigned short* __restrict__ Wd,
    const unsigned short* __restrict__ Sd, unsigned short* __restrict__ HeOut,
    unsigned short* __restrict__ HsOut, float* __restrict__ De, float* __restrict__ Ds,
    const int* __restrict__ list, const int* __restrict__ counts,
    const int* __restrict__ offs) {
  const int h = blockIdx.x;
  const int c = h & 7;
  const int idx = h >> 3;

  int cnt, lda, m0, n0;
  bool routed;
  const unsigned short* A;
  const unsigned short* Bt;
  const int* alist = nullptr;
  unsigned short* H = nullptr;
  float* D = nullptr;
  int ldh = 0;

  if (MODE == 0) {
    if (idx < 128) {
      routed = true;
      n0 = (idx >> 4) * 128; m0 = (idx & 15) * 128;
      cnt = counts[c]; A = Xb; alist = list + offs[c]; lda = 1024;
      Bt = Wgu + (size_t)c * 1048576 + (size_t)(n0 >> 7) * 131072;
      H = HeOut + (size_t)offs[c] * 512; ldh = 512;
    } else {
      routed = false;
      const int t2 = idx - 128;                       // 0..31
      m0 = ((c & 1) * 8 + (t2 & 7)) * 128;
      n0 = ((c >> 1) * 4 + (t2 >> 3)) * 128;
      cnt = 2048; A = Xb; lda = 1024;
      Bt = Sgu + (size_t)(n0 >> 7) * 131072;
      H = HsOut; ldh = 1024;
    }
  } else {
    if (idx < 128) {
      routed = true;
      n0 = (idx >> 4) * 128; m0 = (idx & 15) * 128;
      cnt = counts[c]; A = He + (size_t)offs[c] * 512; lda = 512;
      Bt = Wd + (size_t)c * 524288 + (size_t)(n0 >> 7) * 65536;
      D = De + (size_t)offs[c] * 1024;
    } else {
      routed = false;
      const int t2 = idx - 128;                       // 0..15
      m0 = ((c & 1) * 8 + (t2 & 7)) * 128;
      n0 = ((c >> 1) * 2 + (t2 >> 3)) * 128;
      cnt = 2048; A = Hs; lda = 1024;
      Bt = Sd + (size_t)(n0 >> 7) * 131072;
      D = Ds;
    }
  }
  if (m0 >= cnt) return;

  __shared__ unsigned short As[3 * 4096];   // 3 x 8 KB
  __shared__ unsigned short Bs[3 * 4096];   // 3 x 8 KB

  const int tid = threadIdx.x;
  const int wave = tid >> 6;
  const int lane = tid & 63;
  const int wuni2 = wave * 1024;

  const int achk = ((lane & 3) ^ ((lane >> 3) & 3)) * 8;
  const int arow0 = wave * 32 + (lane >> 2);
  const int arow1 = arow0 + 16;

  int r0 = m0 + arow0; if (r0 >= cnt) r0 = cnt - 1;
  int r1 = m0 + arow1; if (r1 >= cnt) r1 = cnt - 1;
  size_t ab0, ab1;
  if (MODE == 0 && routed) {
    ab0 = (size_t)alist[r0] * lda; ab1 = (size_t)alist[r1] * lda;
  } else {
    ab0 = (size_t)r0 * lda; ab1 = (size_t)r1 * lda;
  }
  const unsigned short* gA0 = A + ab0 + achk;
  const unsigned short* gA1 = A + ab1 + achk;
  const unsigned short* gB = Bt + (wave * 128 + lane) * 8;

  const int wm = (wave & 1) * 64;
  const int wn = (wave >> 1) * 64;
  const int fl = lane & 15;
  const int q = lane >> 4;

  const int cr = (q ^ ((fl >> 1) & 3)) * 8;
  const int aO0 = (wm + fl) * 32 + cr, aO1 = aO0 + 512, aO2 = aO0 + 1024, aO3 = aO0 + 1536;
  const int bO0 = (wn + fl) * 32 + cr, bO1 = bO0 + 512, bO2 = bO0 + 1024, bO3 = bO0 + 1536;

  f32x4 acc[4][4];
  f32x4 zero = {0.f, 0.f, 0.f, 0.f};
#pragma unroll
  for (int i = 0; i < 4; i++)
#pragma unroll
    for (int j = 0; j < 4; j++) acc[i][j] = zero;

  if (MODE == 1 && routed)
    kloop32<16>(gA0, gA1, gB, As, Bs, wuni2, aO0, aO1, aO2, aO3, bO0, bO1, bO2, bO3, acc);
  else
    kloop32<32>(gA0, gA1, gB, As, Bs, wuni2, aO0, aO1, aO2, aO3, bO0, bO1, bO2, bO3, acc);

  if (MODE == 0) {
#pragma unroll
    for (int i = 0; i < 4; i++) {
#pragma unroll
      for (int j = 0; j < 4; j++) {
#pragma unroll
        for (int r = 0; r < 4; r++) {
          int grow = m0 + wm + i * 16 + q * 4 + r;
          float v = acc[i][j][r];
          float pv = __shfl_xor(v, 1);
          if ((lane & 1) == 0 && grow < cnt) {
            float s = v / (1.f + __expf(-v));
            int colh = (n0 + wn + j * 16 + fl) >> 1;
            H[(size_t)grow * ldh + colh] = f2bf(s * pv);
          }
        }
      }
    }
  } else {
#pragma unroll
    for (int i = 0; i < 4; i++) {
#pragma unroll
      for (int r = 0; r < 4; r++) {
        int grow = m0 + wm + i * 16 + q * 4 + r;
        if (grow >= cnt) continue;
#pragma unroll
        for (int j = 0; j < 4; j++) {
          int col = n0 + wn + j * 16 + fl;
          D[(size_t)grow * 1024 + col] = acc[i][j][r];
        }
      }
    }
  }
}

// ---------------- combine ----------------
__global__ __launch_bounds__(256) void combine_kernel(
    const float* __restrict__ Ds, const float* __restrict__ De,
    const int* __restrict__ ridx, const float* __restrict__ rp,
    float* __restrict__ out) {
  const int t = blockIdx.x;
  const int i0 = ridx[t * 2], i1 = ridx[t * 2 + 1];
  const float p0 = rp[t * 2], p1 = rp[t * 2 + 1];
  const float4* a  = (const float4*)(Ds + (size_t)t * 1024);
  const float4* b0 = (const float4*)(De + (size_t)i0 * 1024);
  const float4* b1 = (const float4*)(De + (size_t)i1 * 1024);
  float4* o = (float4*)(out + (size_t)t * 1024);
  int c = threadIdx.x;
  float4 va = a[c], v0 = b0[c], v1 = b1[c];
  float4 r;
  r.x = va.x + p0 * v0.x + p1 * v1.x;
  r.y = va.y + p0 * v0.y + p1 * v1.y;
  r.z = va.z + p0 * v0.z + p1 * v1.z;
  r.w = va.w + p0 * v0.w + p1 * v1.w;
  o[c] = r;
}

// ---------------- launch ----------------
extern "C" void kernel_launch(void* const* d_in, const int* in_sizes, int n_in,
                              void* d_out, int out_size, void* d_ws, size_t ws_size,
                              hipStream_t stream) {
  const float* x    = (const float*)d_in[0];
  const float* Wr   = (const float*)d_in[1];
  const float* Wg   = (const float*)d_in[2];
  const float* Wu   = (const float*)d_in[3];
  const float* Wd   = (const float*)d_in[4];
  const float* Sg   = (const float*)d_in[5];
  const float* Su   = (const float*)d_in[6];
  const float* Sd   = (const float*)d_in[7];
  const float* bias = (const float*)d_in[8];
  float* out = (float*)d_out;

  char* ws = (char*)d_ws;
  size_t o = 0;
  auto alloc = [&](size_t b) { char* p = ws + o; o += (b + 255) & ~(size_t)255; return p; };
  unsigned short* Xb   = (unsigned short*)alloc((size_t)2048 * 1024 * 2);
  unsigned short* WguT = (unsigned short*)alloc((size_t)8 * 1024 * 1024 * 2);
  unsigned short* WdT  = (unsigned short*)alloc((size_t)8 * 1024 * 512 * 2);
  unsigned short* SguT = (unsigned short*)alloc((size_t)2048 * 1024 * 2);
  unsigned short* SdT  = (unsigned short*)alloc((size_t)1024 * 1024 * 2);
  float* logits = (float*)alloc((size_t)2048 * 8 * 4);
  int*   list   = (int*)alloc((size_t)4096 * 4);
  int*   ridx   = (int*)alloc((size_t)2048 * 2 * 4);
  float* rp     = (float*)alloc((size_t)2048 * 2 * 4);
  int*   counts = (int*)alloc(64);
  int*   offs   = (int*)alloc(64);
  unsigned short* He = (unsigned short*)alloc((size_t)4096 * 512 * 2);
  unsigned short* Hs = (unsigned short*)alloc((size_t)2048 * 1024 * 2);
  float* De = (float*)alloc((size_t)4096 * 1024 * 4);
  float* Ds = (float*)alloc((size_t)2048 * 1024 * 4);

  transpose_cvt_all<<<dim3(16, 16, 23), 256, 0, stream>>>(Wg, Wu, Wd, Sg, Su, Sd, x, Wr,
                                                          WguT, WdT, SguT, SdT, Xb, logits);

  assign_kernel<<<1, 1024, 0, stream>>>(logits, bias, list, ridx, rp, counts, offs);

  gemm_tn_kernel<0><<<dim3(1280), 256, 0, stream>>>(
      Xb, He, Hs, WguT, SguT, WdT, SdT, He, Hs, De, Ds, list, counts, offs);
  gemm_tn_kernel<1><<<dim3(1152), 256, 0, stream>>>(
      Xb, He, Hs, WguT, SguT, WdT, SdT, He, Hs, De, Ds, list, counts, offs);

  combine_kernel<<<2048, 256, 0, stream>>>(Ds, De, ridx, rp, out);
}

// Round 14
// 191.398 us; speedup vs baseline: 1.3291x; 1.0033x over previous
//
#include <hip/hip_runtime.h>
#include <cstdint>
#include <cstddef>

typedef __attribute__((ext_vector_type(8))) short bf16x8;
typedef __attribute__((ext_vector_type(4))) float f32x4;

#define AS1 __attribute__((address_space(1)))
#define AS3 __attribute__((address_space(3)))

__device__ __forceinline__ unsigned short f2bf(float f) {
  union { float f; unsigned int u; } v; v.f = f;
  unsigned int r = v.u + 0x7fffu + ((v.u >> 16) & 1u);
  return (unsigned short)(r >> 16);
}

__device__ __forceinline__ void gll16(const unsigned short* g, unsigned short* l) {
  __builtin_amdgcn_global_load_lds((const AS1 void*)g, (AS3 void*)l, 16, 0, 0);
}

// ============================================================================
// Btile layout (BK=32 steps): per (n-panel p of 128 rows, k-step s of 32):
// 512 slots of 16B; slot = r*4 + c4 holds B[n0+r][s*32 + (c4 ^ ((r>>1)&3))*8 .. +8].
// Panel stride = K*128 shorts; step stride = 4096 shorts.
// Gate/up fusion: rows 2f (gate) and 2f+1 (up) share XOR key (f&3) -> same c4;
// their slots are 4 apart (64B), so one thread writing both makes lines dense.
// ============================================================================

// ---------------- weight transposes (tiled, gate/up fused) + x cast + router logits ----------------
// z 0..7: Wg[e]+Wu[e] -> WguT[e] (both parities); z 8..15: Wd[e] -> WdT[e] (K=512)
// z 16: Sg+Su -> SguT; z 17: Sd -> SdT; z 18..21: x -> Xb cast; z 22: logits
__global__ __launch_bounds__(256) void transpose_cvt_all(
    const float* __restrict__ Wg, const float* __restrict__ Wu,
    const float* __restrict__ Wd, const float* __restrict__ Sg,
    const float* __restrict__ Su, const float* __restrict__ Sd,
    const float* __restrict__ x, const float* __restrict__ Wr,
    unsigned short* __restrict__ WguT, unsigned short* __restrict__ WdT,
    unsigned short* __restrict__ SguT, unsigned short* __restrict__ SdT,
    unsigned short* __restrict__ Xb, float* __restrict__ logits) {
  const int z = blockIdx.z;
  const int tid = threadIdx.x;

  if (z == 22) {  // ---- router logits: 8 tokens per block ----
    const int bid = blockIdx.y * 16 + blockIdx.x;   // 0..255
    const int wave = tid >> 6;
    const int lane = tid & 63;
#pragma unroll
    for (int it = 0; it < 2; it++) {
      const int t = bid * 8 + wave * 2 + it;
      const float* xr = x + (size_t)t * 1024;
      float acc[8];
#pragma unroll
      for (int e = 0; e < 8; e++) acc[e] = 0.f;
#pragma unroll
      for (int i = 0; i < 16; i++) {
        int d = lane + i * 64;
        float xv = xr[d];
        const float4* w = (const float4*)(Wr + d * 8);
        float4 w0 = w[0], w1 = w[1];
        acc[0] += xv * w0.x; acc[1] += xv * w0.y; acc[2] += xv * w0.z; acc[3] += xv * w0.w;
        acc[4] += xv * w1.x; acc[5] += xv * w1.y; acc[6] += xv * w1.z; acc[7] += xv * w1.w;
      }
#pragma unroll
      for (int off = 32; off > 0; off >>= 1)
#pragma unroll
        for (int e = 0; e < 8; e++) acc[e] += __shfl_down(acc[e], off);
      if (lane == 0) {
#pragma unroll
        for (int e = 0; e < 8; e++) logits[t * 8 + e] = acc[e];
      }
    }
    return;
  }

  if (z >= 18) {  // ---- copy-cast x (row-major bf16) ----
    size_t off = (size_t)(z - 18) * 524288 + blockIdx.y * 32768 + blockIdx.x * 2048 + tid * 8;
    const float4* s = (const float4*)(x + off);
    float4 a = s[0], b = s[1];
    bf16x8 o = { (short)f2bf(a.x), (short)f2bf(a.y), (short)f2bf(a.z), (short)f2bf(a.w),
                 (short)f2bf(b.x), (short)f2bf(b.y), (short)f2bf(b.z), (short)f2bf(b.w) };
    *(bf16x8*)(Xb + off) = o;
    return;
  }

  __shared__ float tg[64][65];
  __shared__ float tu[64][65];

  if (z < 8 || z == 16) {  // ---- fused gate/up planes ----
    const float* sg_; const float* su_; unsigned short* base; int C;
    if (z < 8) { sg_ = Wg + (size_t)z * 524288; su_ = Wu + (size_t)z * 524288;
                 base = WguT + (size_t)z * 1048576; C = 512; }
    else       { sg_ = Sg; su_ = Su; base = SguT; C = 1024; }
    const int c0 = blockIdx.x * 64, r0 = blockIdx.y * 64;
    if (c0 >= C) return;
    {
      const int row = tid >> 2, cs = (tid & 3) * 16;
      const float* spg = sg_ + (size_t)(r0 + row) * C + c0 + cs;
      const float* spu = su_ + (size_t)(r0 + row) * C + c0 + cs;
#pragma unroll
      for (int k = 0; k < 4; k++) {
        float4 v = ((const float4*)spg)[k];
        tg[row][cs + k * 4 + 0] = v.x; tg[row][cs + k * 4 + 1] = v.y;
        tg[row][cs + k * 4 + 2] = v.z; tg[row][cs + k * 4 + 3] = v.w;
      }
#pragma unroll
      for (int k = 0; k < 4; k++) {
        float4 v = ((const float4*)spu)[k];
        tu[row][cs + k * 4 + 0] = v.x; tu[row][cs + k * 4 + 1] = v.y;
        tu[row][cs + k * 4 + 2] = v.z; tu[row][cs + k * 4 + 3] = v.w;
      }
    }
    __syncthreads();
#pragma unroll
    for (int i = 0; i < 2; i++) {
      const int cc = i * 32 + (tid >> 3);
      const int rseg = (tid & 7) * 8;
      bf16x8 og, ou;
#pragma unroll
      for (int j = 0; j < 8; j++) {
        og[j] = (short)f2bf(tg[rseg + j][cc]);
        ou[j] = (short)f2bf(tu[rseg + j][cc]);
      }
      const int f = c0 + cc;              // gate row 2f, up row 2f+1
      const int k0 = r0 + rseg;
      const int p = f >> 6;               // = (2f)>>7
      const int rg = (2 * f) & 127;
      const int s = k0 >> 5;
      const int c4 = ((k0 >> 3) & 3) ^ (f & 3);   // key (rg>>1)&3 == (ru>>1)&3 == f&3
      unsigned short* d = base + (size_t)p * 131072 + (size_t)s * 4096 + (rg * 4 + c4) * 8;
      *(bf16x8*)d = og;
      *(bf16x8*)(d + 32) = ou;            // slot +4 = 64B -> dense 128B lines
    }
    return;
  }

  // ---- unfused planes: Wd (z 8..15, R=512) / Sd (z 17) ----
  const float* src; unsigned short* base; int R, Ksz;
  if (z < 16) { src = Wd + (size_t)(z - 8) * 524288; base = WdT + (size_t)(z - 8) * 524288; R = 512; Ksz = 512; }
  else        { src = Sd; base = SdT; R = 1024; Ksz = 1024; }
  const int C = 1024;
  const int c0 = blockIdx.x * 64, r0 = blockIdx.y * 64;
  if (r0 >= R) return;
  {
    const int row = tid >> 2, cs = (tid & 3) * 16;
    const float* sp = src + (size_t)(r0 + row) * C + c0 + cs;
#pragma unroll
    for (int k = 0; k < 4; k++) {
      float4 v = ((const float4*)sp)[k];
      tg[row][cs + k * 4 + 0] = v.x; tg[row][cs + k * 4 + 1] = v.y;
      tg[row][cs + k * 4 + 2] = v.z; tg[row][cs + k * 4 + 3] = v.w;
    }
  }
  __syncthreads();
#pragma unroll
  for (int i = 0; i < 2; i++) {
    const int cc = i * 32 + (tid >> 3);
    const int rseg = (tid & 7) * 8;
    bf16x8 o;
#pragma unroll
    for (int j = 0; j < 8; j++) o[j] = (short)f2bf(tg[rseg + j][cc]);
    const int n = c0 + cc;
    const int k0 = r0 + rseg;
    const int p = n >> 7, r = n & 127, s = k0 >> 5;
    const int c4 = ((k0 >> 3) & 3) ^ ((r >> 1) & 3);
    *(bf16x8*)(base + (size_t)p * (Ksz * 128) + (size_t)s * 4096 + (r * 4 + c4) * 8) = o;
  }
}

// ---------------- router: assignment ----------------
__global__ __launch_bounds__(1024) void assign_kernel(
    const float* __restrict__ logits, const float* __restrict__ bias,
    int* __restrict__ list, int* __restrict__ ridx, float* __restrict__ rp,
    int* __restrict__ counts_g, int* __restrict__ offs_g) {
  __shared__ int cnt[8];
  __shared__ int offs[9];
  const int tid = threadIdx.x;
  if (tid < 8) cnt[tid] = 0;
  __syncthreads();
  int te[2][2], tpos[2][2];
  float tp[2][2];
#pragma unroll
  for (int it = 0; it < 2; it++) {
    int t = tid + it * 1024;
    float v[8];
#pragma unroll
    for (int e = 0; e < 8; e++) v[e] = logits[t * 8 + e] + bias[e];
    int i0 = 0;
#pragma unroll
    for (int e = 1; e < 8; e++) if (v[e] > v[i0]) i0 = e;
    int i1 = (i0 == 0) ? 1 : 0;
#pragma unroll
    for (int e = 0; e < 8; e++) if (e != i0 && v[e] > v[i1]) i1 = e;
    float pa = 1.f / (1.f + __expf(v[i1] - v[i0]));
    te[it][0] = i0; te[it][1] = i1;
    tp[it][0] = pa; tp[it][1] = 1.f - pa;
    tpos[it][0] = atomicAdd(&cnt[i0], 1);
    tpos[it][1] = atomicAdd(&cnt[i1], 1);
  }
  __syncthreads();
  if (tid == 0) {
    int s = 0;
#pragma unroll
    for (int e = 0; e < 8; e++) { offs[e] = s; s += cnt[e]; }
    offs[8] = s;
#pragma unroll
    for (int e = 0; e < 8; e++) { counts_g[e] = cnt[e]; offs_g[e] = offs[e]; }
    offs_g[8] = s;
  }
  __syncthreads();
#pragma unroll
  for (int it = 0; it < 2; it++) {
    int t = tid + it * 1024;
#pragma unroll
    for (int k = 0; k < 2; k++) {
      int grow = offs[te[it][k]] + tpos[it][k];
      list[grow] = t;
      ridx[t * 2 + k] = grow;
      rp[t * 2 + k] = tp[it][k];
    }
  }
}

// ---------------- BK=32, 3-buffer, depth-2 prefetch K-loop (proven best) ----------------
#define STAGE4(buf, s) { \
  unsigned short* Ad = As + (buf) * 4096 + wuni2; \
  unsigned short* Bd = Bs + (buf) * 4096 + wuni2; \
  gll16(gA0 + (s) * 32, Ad); \
  gll16(gA1 + (s) * 32, Ad + 512); \
  gll16(gB + (s) * 4096, Bd); \
  gll16(gB + (s) * 4096 + 512, Bd + 512); }

template <int NK>
__device__ __forceinline__ void kloop32(
    const unsigned short* gA0, const unsigned short* gA1,
    const unsigned short* gB,
    unsigned short* As, unsigned short* Bs, const int wuni2,
    const int aO0, const int aO1, const int aO2, const int aO3,
    const int bO0, const int bO1, const int bO2, const int bO3,
    f32x4 (&acc)[4][4]) {
  STAGE4(0, 0);
  STAGE4(1, 1);
#pragma unroll
  for (int i = 0; i < NK; ++i) {
    if (i + 1 < NK) asm volatile("s_waitcnt vmcnt(4) lgkmcnt(0)\n\ts_barrier" ::: "memory");
    else            asm volatile("s_waitcnt vmcnt(0) lgkmcnt(0)\n\ts_barrier" ::: "memory");
    if (i + 2 < NK) { STAGE4((i + 2) % 3, i + 2); }
    const unsigned short* Ab = As + (i % 3) * 4096;
    const unsigned short* Bb = Bs + (i % 3) * 4096;
    bf16x8 af[4], bf[4];
    af[0] = *(const bf16x8*)(Ab + aO0);
    af[1] = *(const bf16x8*)(Ab + aO1);
    af[2] = *(const bf16x8*)(Ab + aO2);
    af[3] = *(const bf16x8*)(Ab + aO3);
    bf[0] = *(const bf16x8*)(Bb + bO0);
    bf[1] = *(const bf16x8*)(Bb + bO1);
    bf[2] = *(const bf16x8*)(Bb + bO2);
    bf[3] = *(const bf16x8*)(Bb + bO3);
    __builtin_amdgcn_s_setprio(1);
#pragma unroll
    for (int ii = 0; ii < 4; ++ii)
#pragma unroll
      for (int jj = 0; jj < 4; ++jj)
        acc[ii][jj] = __builtin_amdgcn_mfma_f32_16x16x32_bf16(af[ii], bf[jj], acc[ii][jj], 0, 0, 0);
    __builtin_amdgcn_s_setprio(0);
  }
}

// ---------------- fused TN GEMM: 128x128 tile, 4 waves, BK=32, XCD-class remap ----------------
template <int MODE>
__global__ __launch_bounds__(256, 3) void gemm_tn_kernel(
    const unsigned short* __restrict__ Xb, const unsigned short* __restrict__ He,
    const unsigned short* __restrict__ Hs, const unsigned short* __restrict__ Wgu,
    const unsigned short* __restrict__ Sgu, const unsigned short* __restrict__ Wd,
    const unsigned short* __restrict__ Sd, unsigned short* __restrict__ HeOut,
    unsigned short* __restrict__ HsOut, float* __restrict__ De, float* __restrict__ Ds,
    const int* __restrict__ list, const int* __restrict__ counts,
    const int* __restrict__ offs) {
  const int h = blockIdx.x;
  const int c = h & 7;
  const int idx = h >> 3;

  int cnt, lda, m0, n0;
  bool routed;
  const unsigned short* A;
  const unsigned short* Bt;
  const int* alist = nullptr;
  unsigned short* H = nullptr;
  float* D = nullptr;
  int ldh = 0;

  if (MODE == 0) {
    if (idx < 128) {
      routed = true;
      n0 = (idx >> 4) * 128; m0 = (idx & 15) * 128;
      cnt = counts[c]; A = Xb; alist = list + offs[c]; lda = 1024;
      Bt = Wgu + (size_t)c * 1048576 + (size_t)(n0 >> 7) * 131072;
      H = HeOut + (size_t)offs[c] * 512; ldh = 512;
    } else {
      routed = false;
      const int t2 = idx - 128;                       // 0..31
      m0 = ((c & 1) * 8 + (t2 & 7)) * 128;
      n0 = ((c >> 1) * 4 + (t2 >> 3)) * 128;
      cnt = 2048; A = Xb; lda = 1024;
      Bt = Sgu + (size_t)(n0 >> 7) * 131072;
      H = HsOut; ldh = 1024;
    }
  } else {
    if (idx < 128) {
      routed = true;
      n0 = (idx >> 4) * 128; m0 = (idx & 15) * 128;
      cnt = counts[c]; A = He + (size_t)offs[c] * 512; lda = 512;
      Bt = Wd + (size_t)c * 524288 + (size_t)(n0 >> 7) * 65536;
      D = De + (size_t)offs[c] * 1024;
    } else {
      routed = false;
      const int t2 = idx - 128;                       // 0..15
      m0 = ((c & 1) * 8 + (t2 & 7)) * 128;
      n0 = ((c >> 1) * 2 + (t2 >> 3)) * 128;
      cnt = 2048; A = Hs; lda = 1024;
      Bt = Sd + (size_t)(n0 >> 7) * 131072;
      D = Ds;
    }
  }
  if (m0 >= cnt) return;

  __shared__ unsigned short As[3 * 4096];   // 3 x 8 KB
  __shared__ unsigned short Bs[3 * 4096];   // 3 x 8 KB

  const int tid = threadIdx.x;
  const int wave = tid >> 6;
  const int lane = tid & 63;
  const int wuni2 = wave * 1024;

  const int achk = ((lane & 3) ^ ((lane >> 3) & 3)) * 8;
  const int arow0 = wave * 32 + (lane >> 2);
  const int arow1 = arow0 + 16;

  int r0 = m0 + arow0; if (r0 >= cnt) r0 = cnt - 1;
  int r1 = m0 + arow1; if (r1 >= cnt) r1 = cnt - 1;
  size_t ab0, ab1;
  if (MODE == 0 && routed) {
    ab0 = (size_t)alist[r0] * lda; ab1 = (size_t)alist[r1] * lda;
  } else {
    ab0 = (size_t)r0 * lda; ab1 = (size_t)r1 * lda;
  }
  const unsigned short* gA0 = A + ab0 + achk;
  const unsigned short* gA1 = A + ab1 + achk;
  const unsigned short* gB = Bt + (wave * 128 + lane) * 8;

  const int wm = (wave & 1) * 64;
  const int wn = (wave >> 1) * 64;
  const int fl = lane & 15;
  const int q = lane >> 4;

  const int cr = (q ^ ((fl >> 1) & 3)) * 8;
  const int aO0 = (wm + fl) * 32 + cr, aO1 = aO0 + 512, aO2 = aO0 + 1024, aO3 = aO0 + 1536;
  const int bO0 = (wn + fl) * 32 + cr, bO1 = bO0 + 512, bO2 = bO0 + 1024, bO3 = bO0 + 1536;

  f32x4 acc[4][4];
  f32x4 zero = {0.f, 0.f, 0.f, 0.f};
#pragma unroll
  for (int i = 0; i < 4; i++)
#pragma unroll
    for (int j = 0; j < 4; j++) acc[i][j] = zero;

  if (MODE == 1 && routed)
    kloop32<16>(gA0, gA1, gB, As, Bs, wuni2, aO0, aO1, aO2, aO3, bO0, bO1, bO2, bO3, acc);
  else
    kloop32<32>(gA0, gA1, gB, As, Bs, wuni2, aO0, aO1, aO2, aO3, bO0, bO1, bO2, bO3, acc);

  if (MODE == 0) {
#pragma unroll
    for (int i = 0; i < 4; i++) {
#pragma unroll
      for (int j = 0; j < 4; j++) {
#pragma unroll
        for (int r = 0; r < 4; r++) {
          int grow = m0 + wm + i * 16 + q * 4 + r;
          float v = acc[i][j][r];
          float pv = __shfl_xor(v, 1);
          if ((lane & 1) == 0 && grow < cnt) {
            float s = v / (1.f + __expf(-v));
            int colh = (n0 + wn + j * 16 + fl) >> 1;
            H[(size_t)grow * ldh + colh] = f2bf(s * pv);
          }
        }
      }
    }
  } else {
#pragma unroll
    for (int i = 0; i < 4; i++) {
#pragma unroll
      for (int r = 0; r < 4; r++) {
        int grow = m0 + wm + i * 16 + q * 4 + r;
        if (grow >= cnt) continue;
#pragma unroll
        for (int j = 0; j < 4; j++) {
          int col = n0 + wn + j * 16 + fl;
          D[(size_t)grow * 1024 + col] = acc[i][j][r];
        }
      }
    }
  }
}

// ---------------- combine ----------------
__global__ __launch_bounds__(256) void combine_kernel(
    const float* __restrict__ Ds, const float* __restrict__ De,
    const int* __restrict__ ridx, const float* __restrict__ rp,
    float* __restrict__ out) {
  const int t = blockIdx.x;
  const int i0 = ridx[t * 2], i1 = ridx[t * 2 + 1];
  const float p0 = rp[t * 2], p1 = rp[t * 2 + 1];
  const float4* a  = (const float4*)(Ds + (size_t)t * 1024);
  const float4* b0 = (const float4*)(De + (size_t)i0 * 1024);
  const float4* b1 = (const float4*)(De + (size_t)i1 * 1024);
  float4* o = (float4*)(out + (size_t)t * 1024);
  int c = threadIdx.x;
  float4 va = a[c], v0 = b0[c], v1 = b1[c];
  float4 r;
  r.x = va.x + p0 * v0.x + p1 * v1.x;
  r.y = va.y + p0 * v0.y + p1 * v1.y;
  r.z = va.z + p0 * v0.z + p1 * v1.z;
  r.w = va.w + p0 * v0.w + p1 * v1.w;
  o[c] = r;
}

// ---------------- launch ----------------
extern "C" void kernel_launch(void* const* d_in, const int* in_sizes, int n_in,
                              void* d_out, int out_size, void* d_ws, size_t ws_size,
                              hipStream_t stream) {
  const float* x    = (const float*)d_in[0];
  const float* Wr   = (const float*)d_in[1];
  const float* Wg   = (const float*)d_in[2];
  const float* Wu   = (const float*)d_in[3];
  const float* Wd   = (const float*)d_in[4];
  const float* Sg   = (const float*)d_in[5];
  const float* Su   = (const float*)d_in[6];
  const float* Sd   = (const float*)d_in[7];
  const float* bias = (const float*)d_in[8];
  float* out = (float*)d_out;

  char* ws = (char*)d_ws;
  size_t o = 0;
  auto alloc = [&](size_t b) { char* p = ws + o; o += (b + 255) & ~(size_t)255; return p; };
  unsigned short* Xb   = (unsigned short*)alloc((size_t)2048 * 1024 * 2);
  unsigned short* WguT = (unsigned short*)alloc((size_t)8 * 1024 * 1024 * 2);
  unsigned short* WdT  = (unsigned short*)alloc((size_t)8 * 1024 * 512 * 2);
  unsigned short* SguT = (unsigned short*)alloc((size_t)2048 * 1024 * 2);
  unsigned short* SdT  = (unsigned short*)alloc((size_t)1024 * 1024 * 2);
  float* logits = (float*)alloc((size_t)2048 * 8 * 4);
  int*   list   = (int*)alloc((size_t)4096 * 4);
  int*   ridx   = (int*)alloc((size_t)2048 * 2 * 4);
  float* rp     = (float*)alloc((size_t)2048 * 2 * 4);
  int*   counts = (int*)alloc(64);
  int*   offs   = (int*)alloc(64);
  unsigned short* He = (unsigned short*)alloc((size_t)4096 * 512 * 2);
  unsigned short* Hs = (unsigned short*)alloc((size_t)2048 * 1024 * 2);
  float* De = (float*)alloc((size_t)4096 * 1024 * 4);
  float* Ds = (float*)alloc((size_t)2048 * 1024 * 4);

  transpose_cvt_all<<<dim3(16, 16, 23), 256, 0, stream>>>(Wg, Wu, Wd, Sg, Su, Sd, x, Wr,
                                                          WguT, WdT, SguT, SdT, Xb, logits);

  assign_kernel<<<1, 1024, 0, stream>>>(logits, bias, list, ridx, rp, counts, offs);

  gemm_tn_kernel<0><<<dim3(1280), 256, 0, stream>>>(
      Xb, He, Hs, WguT, SguT, WdT, SdT, He, Hs, De, Ds, list, counts, offs);
  gemm_tn_kernel<1><<<dim3(1152), 256, 0, stream>>>(
      Xb, He, Hs, WguT, SguT, WdT, SdT, He, Hs, De, Ds, list, counts, offs);

  combine_kernel<<<2048, 256, 0, stream>>>(Ds, De, ridx, rp, out);
}

// Round 15
// 188.843 us; speedup vs baseline: 1.3470x; 1.0135x over previous
//
#include <hip/hip_runtime.h>
#include <cstdint>
#include <cstddef>

typedef __attribute__((ext_vector_type(8))) short bf16x8;
typedef __attribute__((ext_vector_type(4))) float f32x4;

#define AS1 __attribute__((address_space(1)))
#define AS3 __attribute__((address_space(3)))

__device__ __forceinline__ unsigned short f2bf(float f) {
  union { float f; unsigned int u; } v; v.f = f;
  unsigned int r = v.u + 0x7fffu + ((v.u >> 16) & 1u);
  return (unsigned short)(r >> 16);
}

__device__ __forceinline__ void gll16(const unsigned short* g, unsigned short* l) {
  __builtin_amdgcn_global_load_lds((const AS1 void*)g, (AS3 void*)l, 16, 0, 0);
}

// ============================================================================
// Btile layout (BK=32 steps): per (n-panel p of 128 rows, k-step s of 32):
// 512 slots of 16B; slot = r*4 + c4 holds B[n0+r][s*32 + (c4 ^ ((r>>1)&3))*8 .. +8].
// Panel stride = K*128 shorts; step stride = 4096 shorts.
// Gate/up fusion: rows 2f (gate) and 2f+1 (up) share XOR key (f&3) -> same c4;
// their slots are 4 apart (64B), so one thread writing both makes lines dense.
// ============================================================================

// ---------------- weight transposes (tiled, gate/up fused) + x cast + router logits ----------------
// z 0..7: Wg[e]+Wu[e] -> WguT[e] (both parities); z 8..15: Wd[e] -> WdT[e] (K=512)
// z 16: Sg+Su -> SguT; z 17: Sd -> SdT; z 18..21: x -> Xb cast; z 22: logits
__global__ __launch_bounds__(256) void transpose_cvt_all(
    const float* __restrict__ Wg, const float* __restrict__ Wu,
    const float* __restrict__ Wd, const float* __restrict__ Sg,
    const float* __restrict__ Su, const float* __restrict__ Sd,
    const float* __restrict__ x, const float* __restrict__ Wr,
    unsigned short* __restrict__ WguT, unsigned short* __restrict__ WdT,
    unsigned short* __restrict__ SguT, unsigned short* __restrict__ SdT,
    unsigned short* __restrict__ Xb, float* __restrict__ logits) {
  const int z = blockIdx.z;
  const int tid = threadIdx.x;

  if (z == 22) {  // ---- router logits: 8 tokens per block ----
    const int bid = blockIdx.y * 16 + blockIdx.x;   // 0..255
    const int wave = tid >> 6;
    const int lane = tid & 63;
#pragma unroll
    for (int it = 0; it < 2; it++) {
      const int t = bid * 8 + wave * 2 + it;
      const float* xr = x + (size_t)t * 1024;
      float acc[8];
#pragma unroll
      for (int e = 0; e < 8; e++) acc[e] = 0.f;
#pragma unroll
      for (int i = 0; i < 16; i++) {
        int d = lane + i * 64;
        float xv = xr[d];
        const float4* w = (const float4*)(Wr + d * 8);
        float4 w0 = w[0], w1 = w[1];
        acc[0] += xv * w0.x; acc[1] += xv * w0.y; acc[2] += xv * w0.z; acc[3] += xv * w0.w;
        acc[4] += xv * w1.x; acc[5] += xv * w1.y; acc[6] += xv * w1.z; acc[7] += xv * w1.w;
      }
#pragma unroll
      for (int off = 32; off > 0; off >>= 1)
#pragma unroll
        for (int e = 0; e < 8; e++) acc[e] += __shfl_down(acc[e], off);
      if (lane == 0) {
#pragma unroll
        for (int e = 0; e < 8; e++) logits[t * 8 + e] = acc[e];
      }
    }
    return;
  }

  if (z >= 18) {  // ---- copy-cast x (row-major bf16) ----
    size_t off = (size_t)(z - 18) * 524288 + blockIdx.y * 32768 + blockIdx.x * 2048 + tid * 8;
    const float4* s = (const float4*)(x + off);
    float4 a = s[0], b = s[1];
    bf16x8 o = { (short)f2bf(a.x), (short)f2bf(a.y), (short)f2bf(a.z), (short)f2bf(a.w),
                 (short)f2bf(b.x), (short)f2bf(b.y), (short)f2bf(b.z), (short)f2bf(b.w) };
    *(bf16x8*)(Xb + off) = o;
    return;
  }

  __shared__ float tg[64][65];
  __shared__ float tu[64][65];

  if (z < 8 || z == 16) {  // ---- fused gate/up planes ----
    const float* sg_; const float* su_; unsigned short* base; int C;
    if (z < 8) { sg_ = Wg + (size_t)z * 524288; su_ = Wu + (size_t)z * 524288;
                 base = WguT + (size_t)z * 1048576; C = 512; }
    else       { sg_ = Sg; su_ = Su; base = SguT; C = 1024; }
    const int c0 = blockIdx.x * 64, r0 = blockIdx.y * 64;
    if (c0 >= C) return;
    {
      const int row = tid >> 2, cs = (tid & 3) * 16;
      const float* spg = sg_ + (size_t)(r0 + row) * C + c0 + cs;
      const float* spu = su_ + (size_t)(r0 + row) * C + c0 + cs;
#pragma unroll
      for (int k = 0; k < 4; k++) {
        float4 v = ((const float4*)spg)[k];
        tg[row][cs + k * 4 + 0] = v.x; tg[row][cs + k * 4 + 1] = v.y;
        tg[row][cs + k * 4 + 2] = v.z; tg[row][cs + k * 4 + 3] = v.w;
      }
#pragma unroll
      for (int k = 0; k < 4; k++) {
        float4 v = ((const float4*)spu)[k];
        tu[row][cs + k * 4 + 0] = v.x; tu[row][cs + k * 4 + 1] = v.y;
        tu[row][cs + k * 4 + 2] = v.z; tu[row][cs + k * 4 + 3] = v.w;
      }
    }
    __syncthreads();
#pragma unroll
    for (int i = 0; i < 2; i++) {
      const int cc = i * 32 + (tid >> 3);
      const int rseg = (tid & 7) * 8;
      bf16x8 og, ou;
#pragma unroll
      for (int j = 0; j < 8; j++) {
        og[j] = (short)f2bf(tg[rseg + j][cc]);
        ou[j] = (short)f2bf(tu[rseg + j][cc]);
      }
      const int f = c0 + cc;              // gate row 2f, up row 2f+1
      const int k0 = r0 + rseg;
      const int p = f >> 6;               // = (2f)>>7
      const int rg = (2 * f) & 127;
      const int s = k0 >> 5;
      const int c4 = ((k0 >> 3) & 3) ^ (f & 3);   // key (rg>>1)&3 == (ru>>1)&3 == f&3
      unsigned short* d = base + (size_t)p * 131072 + (size_t)s * 4096 + (rg * 4 + c4) * 8;
      *(bf16x8*)d = og;
      *(bf16x8*)(d + 32) = ou;            // slot +4 = 64B -> dense 128B lines
    }
    return;
  }

  // ---- unfused planes: Wd (z 8..15, R=512) / Sd (z 17) ----
  const float* src; unsigned short* base; int R, Ksz;
  if (z < 16) { src = Wd + (size_t)(z - 8) * 524288; base = WdT + (size_t)(z - 8) * 524288; R = 512; Ksz = 512; }
  else        { src = Sd; base = SdT; R = 1024; Ksz = 1024; }
  const int C = 1024;
  const int c0 = blockIdx.x * 64, r0 = blockIdx.y * 64;
  if (r0 >= R) return;
  {
    const int row = tid >> 2, cs = (tid & 3) * 16;
    const float* sp = src + (size_t)(r0 + row) * C + c0 + cs;
#pragma unroll
    for (int k = 0; k < 4; k++) {
      float4 v = ((const float4*)sp)[k];
      tg[row][cs + k * 4 + 0] = v.x; tg[row][cs + k * 4 + 1] = v.y;
      tg[row][cs + k * 4 + 2] = v.z; tg[row][cs + k * 4 + 3] = v.w;
    }
  }
  __syncthreads();
#pragma unroll
  for (int i = 0; i < 2; i++) {
    const int cc = i * 32 + (tid >> 3);
    const int rseg = (tid & 7) * 8;
    bf16x8 o;
#pragma unroll
    for (int j = 0; j < 8; j++) o[j] = (short)f2bf(tg[rseg + j][cc]);
    const int n = c0 + cc;
    const int k0 = r0 + rseg;
    const int p = n >> 7, r = n & 127, s = k0 >> 5;
    const int c4 = ((k0 >> 3) & 3) ^ ((r >> 1) & 3);
    *(bf16x8*)(base + (size_t)p * (Ksz * 128) + (size_t)s * 4096 + (r * 4 + c4) * 8) = o;
  }
}

// ---------------- router: assignment ----------------
__global__ __launch_bounds__(1024) void assign_kernel(
    const float* __restrict__ logits, const float* __restrict__ bias,
    int* __restrict__ list, int* __restrict__ ridx, float* __restrict__ rp,
    int* __restrict__ counts_g, int* __restrict__ offs_g) {
  __shared__ int cnt[8];
  __shared__ int offs[9];
  const int tid = threadIdx.x;
  if (tid < 8) cnt[tid] = 0;
  __syncthreads();
  int te[2][2], tpos[2][2];
  float tp[2][2];
#pragma unroll
  for (int it = 0; it < 2; it++) {
    int t = tid + it * 1024;
    float v[8];
#pragma unroll
    for (int e = 0; e < 8; e++) v[e] = logits[t * 8 + e] + bias[e];
    int i0 = 0;
#pragma unroll
    for (int e = 1; e < 8; e++) if (v[e] > v[i0]) i0 = e;
    int i1 = (i0 == 0) ? 1 : 0;
#pragma unroll
    for (int e = 0; e < 8; e++) if (e != i0 && v[e] > v[i1]) i1 = e;
    float pa = 1.f / (1.f + __expf(v[i1] - v[i0]));
    te[it][0] = i0; te[it][1] = i1;
    tp[it][0] = pa; tp[it][1] = 1.f - pa;
    tpos[it][0] = atomicAdd(&cnt[i0], 1);
    tpos[it][1] = atomicAdd(&cnt[i1], 1);
  }
  __syncthreads();
  if (tid == 0) {
    int s = 0;
#pragma unroll
    for (int e = 0; e < 8; e++) { offs[e] = s; s += cnt[e]; }
    offs[8] = s;
#pragma unroll
    for (int e = 0; e < 8; e++) { counts_g[e] = cnt[e]; offs_g[e] = offs[e]; }
    offs_g[8] = s;
  }
  __syncthreads();
#pragma unroll
  for (int it = 0; it < 2; it++) {
    int t = tid + it * 1024;
#pragma unroll
    for (int k = 0; k < 2; k++) {
      int grow = offs[te[it][k]] + tpos[it][k];
      list[grow] = t;
      ridx[t * 2 + k] = grow;
      rp[t * 2 + k] = tp[it][k];
    }
  }
}

// ---------------- BK=32, 3-buffer, depth-2 prefetch K-loop (proven best) ----------------
#define STAGE4(buf, s) { \
  unsigned short* Ad = As + (buf) * 4096 + wuni2; \
  unsigned short* Bd = Bs + (buf) * 4096 + wuni2; \
  gll16(gA0 + (s) * 32, Ad); \
  gll16(gA1 + (s) * 32, Ad + 512); \
  gll16(gB + (s) * 4096, Bd); \
  gll16(gB + (s) * 4096 + 512, Bd + 512); }

template <int NK>
__device__ __forceinline__ void kloop32(
    const unsigned short* gA0, const unsigned short* gA1,
    const unsigned short* gB,
    unsigned short* As, unsigned short* Bs, const int wuni2,
    const int aO0, const int aO1, const int aO2, const int aO3,
    const int bO0, const int bO1, const int bO2, const int bO3,
    f32x4 (&acc)[4][4]) {
  STAGE4(0, 0);
  STAGE4(1, 1);
#pragma unroll
  for (int i = 0; i < NK; ++i) {
    if (i + 1 < NK) asm volatile("s_waitcnt vmcnt(4) lgkmcnt(0)\n\ts_barrier" ::: "memory");
    else            asm volatile("s_waitcnt vmcnt(0) lgkmcnt(0)\n\ts_barrier" ::: "memory");
    if (i + 2 < NK) { STAGE4((i + 2) % 3, i + 2); }
    const unsigned short* Ab = As + (i % 3) * 4096;
    const unsigned short* Bb = Bs + (i % 3) * 4096;
    bf16x8 af[4], bf[4];
    af[0] = *(const bf16x8*)(Ab + aO0);
    af[1] = *(const bf16x8*)(Ab + aO1);
    af[2] = *(const bf16x8*)(Ab + aO2);
    af[3] = *(const bf16x8*)(Ab + aO3);
    bf[0] = *(const bf16x8*)(Bb + bO0);
    bf[1] = *(const bf16x8*)(Bb + bO1);
    bf[2] = *(const bf16x8*)(Bb + bO2);
    bf[3] = *(const bf16x8*)(Bb + bO3);
    __builtin_amdgcn_s_setprio(1);
#pragma unroll
    for (int ii = 0; ii < 4; ++ii)
#pragma unroll
      for (int jj = 0; jj < 4; ++jj)
        acc[ii][jj] = __builtin_amdgcn_mfma_f32_16x16x32_bf16(af[ii], bf[jj], acc[ii][jj], 0, 0, 0);
    __builtin_amdgcn_s_setprio(0);
  }
}

// ---------------- fused TN GEMM: 128x128 tile, 4 waves, BK=32, XCD-class remap ----------------
template <int MODE>
__global__ __launch_bounds__(256, 3) void gemm_tn_kernel(
    const unsigned short* __restrict__ Xb, const unsigned short* __restrict__ He,
    const unsigned short* __restrict__ Hs, const unsigned short* __restrict__ Wgu,
    const unsigned short* __restrict__ Sgu, const unsigned short* __restrict__ Wd,
    const unsigned short* __restrict__ Sd, unsigned short* __restrict__ HeOut,
    unsigned short* __restrict__ HsOut, float* __restrict__ De, float* __restrict__ Ds,
    const int* __restrict__ list, const int* __restrict__ counts,
    const int* __restrict__ offs) {
  const int h = blockIdx.x;
  const int c = h & 7;
  const int idx = h >> 3;

  int cnt, lda, m0, n0;
  bool routed;
  const unsigned short* A;
  const unsigned short* Bt;
  const int* alist = nullptr;
  unsigned short* H = nullptr;
  float* D = nullptr;
  int ldh = 0;

  if (MODE == 0) {
    if (idx < 128) {
      routed = true;
      n0 = (idx >> 4) * 128; m0 = (idx & 15) * 128;
      cnt = counts[c]; A = Xb; alist = list + offs[c]; lda = 1024;
      Bt = Wgu + (size_t)c * 1048576 + (size_t)(n0 >> 7) * 131072;
      H = HeOut + (size_t)offs[c] * 512; ldh = 512;
    } else {
      routed = false;
      const int t2 = idx - 128;                       // 0..31
      m0 = ((c & 1) * 8 + (t2 & 7)) * 128;
      n0 = ((c >> 1) * 4 + (t2 >> 3)) * 128;
      cnt = 2048; A = Xb; lda = 1024;
      Bt = Sgu + (size_t)(n0 >> 7) * 131072;
      H = HsOut; ldh = 1024;
    }
  } else {
    if (idx < 128) {
      routed = true;
      n0 = (idx >> 4) * 128; m0 = (idx & 15) * 128;
      cnt = counts[c]; A = He + (size_t)offs[c] * 512; lda = 512;
      Bt = Wd + (size_t)c * 524288 + (size_t)(n0 >> 7) * 65536;
      D = De + (size_t)offs[c] * 1024;
    } else {
      routed = false;
      const int t2 = idx - 128;                       // 0..15
      m0 = ((c & 1) * 8 + (t2 & 7)) * 128;
      n0 = ((c >> 1) * 2 + (t2 >> 3)) * 128;
      cnt = 2048; A = Hs; lda = 1024;
      Bt = Sd + (size_t)(n0 >> 7) * 131072;
      D = Ds;
    }
  }
  if (m0 >= cnt) return;

  __shared__ unsigned short As[3 * 4096];   // 3 x 8 KB
  __shared__ unsigned short Bs[3 * 4096];   // 3 x 8 KB

  const int tid = threadIdx.x;
  const int wave = tid >> 6;
  const int lane = tid & 63;
  const int wuni2 = wave * 1024;

  const int achk = ((lane & 3) ^ ((lane >> 3) & 3)) * 8;
  const int arow0 = wave * 32 + (lane >> 2);
  const int arow1 = arow0 + 16;

  int r0 = m0 + arow0; if (r0 >= cnt) r0 = cnt - 1;
  int r1 = m0 + arow1; if (r1 >= cnt) r1 = cnt - 1;
  size_t ab0, ab1;
  if (MODE == 0 && routed) {
    ab0 = (size_t)alist[r0] * lda; ab1 = (size_t)alist[r1] * lda;
  } else {
    ab0 = (size_t)r0 * lda; ab1 = (size_t)r1 * lda;
  }
  const unsigned short* gA0 = A + ab0 + achk;
  const unsigned short* gA1 = A + ab1 + achk;
  const unsigned short* gB = Bt + (wave * 128 + lane) * 8;

  const int wm = (wave & 1) * 64;
  const int wn = (wave >> 1) * 64;
  const int fl = lane & 15;
  const int q = lane >> 4;

  const int cr = (q ^ ((fl >> 1) & 3)) * 8;
  const int aO0 = (wm + fl) * 32 + cr, aO1 = aO0 + 512, aO2 = aO0 + 1024, aO3 = aO0 + 1536;
  const int bO0 = (wn + fl) * 32 + cr, bO1 = bO0 + 512, bO2 = bO0 + 1024, bO3 = bO0 + 1536;

  f32x4 acc[4][4];
  f32x4 zero = {0.f, 0.f, 0.f, 0.f};
#pragma unroll
  for (int i = 0; i < 4; i++)
#pragma unroll
    for (int j = 0; j < 4; j++) acc[i][j] = zero;

  if (MODE == 1 && routed)
    kloop32<16>(gA0, gA1, gB, As, Bs, wuni2, aO0, aO1, aO2, aO3, bO0, bO1, bO2, bO3, acc);
  else
    kloop32<32>(gA0, gA1, gB, As, Bs, wuni2, aO0, aO1, aO2, aO3, bO0, bO1, bO2, bO3, acc);

  if (MODE == 0) {
#pragma unroll
    for (int i = 0; i < 4; i++) {
#pragma unroll
      for (int j = 0; j < 4; j++) {
#pragma unroll
        for (int r = 0; r < 4; r++) {
          int grow = m0 + wm + i * 16 + q * 4 + r;
          float v = acc[i][j][r];
          float pv = __shfl_xor(v, 1);
          if ((lane & 1) == 0 && grow < cnt) {
            float s = v / (1.f + __expf(-v));
            int colh = (n0 + wn + j * 16 + fl) >> 1;
            H[(size_t)grow * ldh + colh] = f2bf(s * pv);
          }
        }
      }
    }
  } else {
#pragma unroll
    for (int i = 0; i < 4; i++) {
#pragma unroll
      for (int r = 0; r < 4; r++) {
        int grow = m0 + wm + i * 16 + q * 4 + r;
        if (grow >= cnt) continue;
#pragma unroll
        for (int j = 0; j < 4; j++) {
          int col = n0 + wn + j * 16 + fl;
          D[(size_t)grow * 1024 + col] = acc[i][j][r];
        }
      }
    }
  }
}

// ---------------- combine ----------------
__global__ __launch_bounds__(256) void combine_kernel(
    const float* __restrict__ Ds, const float* __restrict__ De,
    const int* __restrict__ ridx, const float* __restrict__ rp,
    float* __restrict__ out) {
  const int t = blockIdx.x;
  const int i0 = ridx[t * 2], i1 = ridx[t * 2 + 1];
  const float p0 = rp[t * 2], p1 = rp[t * 2 + 1];
  const float4* a  = (const float4*)(Ds + (size_t)t * 1024);
  const float4* b0 = (const float4*)(De + (size_t)i0 * 1024);
  const float4* b1 = (const float4*)(De + (size_t)i1 * 1024);
  float4* o = (float4*)(out + (size_t)t * 1024);
  int c = threadIdx.x;
  float4 va = a[c], v0 = b0[c], v1 = b1[c];
  float4 r;
  r.x = va.x + p0 * v0.x + p1 * v1.x;
  r.y = va.y + p0 * v0.y + p1 * v1.y;
  r.z = va.z + p0 * v0.z + p1 * v1.z;
  r.w = va.w + p0 * v0.w + p1 * v1.w;
  o[c] = r;
}

// ---------------- launch ----------------
extern "C" void kernel_launch(void* const* d_in, const int* in_sizes, int n_in,
                              void* d_out, int out_size, void* d_ws, size_t ws_size,
                              hipStream_t stream) {
  const float* x    = (const float*)d_in[0];
  const float* Wr   = (const float*)d_in[1];
  const float* Wg   = (const float*)d_in[2];
  const float* Wu   = (const float*)d_in[3];
  const float* Wd   = (const float*)d_in[4];
  const float* Sg   = (const float*)d_in[5];
  const float* Su   = (const float*)d_in[6];
  const float* Sd   = (const float*)d_in[7];
  const float* bias = (const float*)d_in[8];
  float* out = (float*)d_out;

  char* ws = (char*)d_ws;
  size_t o = 0;
  auto alloc = [&](size_t b) { char* p = ws + o; o += (b + 255) & ~(size_t)255; return p; };
  unsigned short* Xb   = (unsigned short*)alloc((size_t)2048 * 1024 * 2);
  unsigned short* WguT = (unsigned short*)alloc((size_t)8 * 1024 * 1024 * 2);
  unsigned short* WdT  = (unsigned short*)alloc((size_t)8 * 1024 * 512 * 2);
  unsigned short* SguT = (unsigned short*)alloc((size_t)2048 * 1024 * 2);
  unsigned short* SdT  = (unsigned short*)alloc((size_t)1024 * 1024 * 2);
  float* logits = (float*)alloc((size_t)2048 * 8 * 4);
  int*   list   = (int*)alloc((size_t)4096 * 4);
  int*   ridx   = (int*)alloc((size_t)2048 * 2 * 4);
  float* rp     = (float*)alloc((size_t)2048 * 2 * 4);
  int*   counts = (int*)alloc(64);
  int*   offs   = (int*)alloc(64);
  unsigned short* He = (unsigned short*)alloc((size_t)4096 * 512 * 2);
  unsigned short* Hs = (unsigned short*)alloc((size_t)2048 * 1024 * 2);
  float* De = (float*)alloc((size_t)4096 * 1024 * 4);
  float* Ds = (float*)alloc((size_t)2048 * 1024 * 4);

  transpose_cvt_all<<<dim3(16, 16, 23), 256, 0, stream>>>(Wg, Wu, Wd, Sg, Su, Sd, x, Wr,
                                                          WguT, WdT, SguT, SdT, Xb, logits);

  assign_kernel<<<1, 1024, 0, stream>>>(logits, bias, list, ridx, rp, counts, offs);

  gemm_tn_kernel<0><<<dim3(1280), 256, 0, stream>>>(
      Xb, He, Hs, WguT, SguT, WdT, SdT, He, Hs, De, Ds, list, counts, offs);
  gemm_tn_kernel<1><<<dim3(1152), 256, 0, stream>>>(
      Xb, He, Hs, WguT, SguT, WdT, SdT, He, Hs, De, Ds, list, counts, offs);

  combine_kernel<<<2048, 256, 0, stream>>>(Ds, De, ridx, rp, out);
}